// Round 8
// baseline (1579.188 us; speedup 1.0000x reference)
//
#include <hip/hip_runtime.h>
#include <hip/hip_bf16.h>
#include <math.h>

#define HID 128
#define KRBF 9
#define NLAYER 3
#define QWCOLS 640  // packed qkvs weight cols: 5 blocks of 128 (q|k|v|skip|QW+pad)
#define WPAD 142    // LDS row stride (halfwords): 71 dwords, odd -> <=2-way banks (free)

typedef __attribute__((ext_vector_type(8))) short bf16x8;
typedef __attribute__((ext_vector_type(4))) float f32x4;

__device__ __forceinline__ float sp_(float x){ return fmaxf(x,0.f) + log1pf(expf(-fabsf(x))); }
__device__ __forceinline__ float sigm_(float x){ return 1.f/(1.f+expf(-x)); }
__device__ __forceinline__ float b2f(short s){
  union{unsigned u; float f;} x; x.u = ((unsigned)(unsigned short)s)<<16; return x.f;
}
__device__ __forceinline__ short f2bs(float x){
  __hip_bfloat16 b = __float2bfloat16(x);
  return *reinterpret_cast<short*>(&b);
}
__device__ __forceinline__ float wsum64(float v){
  #pragma unroll
  for(int m=1;m<64;m<<=1) v += __shfl_xor(v,m,64);
  return v;
}
__device__ __forceinline__ float wsum16(float v){
  #pragma unroll
  for(int m=1;m<16;m<<=1) v += __shfl_xor(v,m,64);
  return v;
}
__device__ __forceinline__ int lb_(const int* __restrict__ a, int n, int key){
  int lo=0, hi=n;
  while(lo<hi){ int mid=(lo+hi)>>1; if(a[mid]<key) lo=mid+1; else hi=mid; }
  return lo;
}

// ---------------- CSR counts ----------------
__global__ void count_dst(const int* __restrict__ ei, int* __restrict__ counts, int E){
  int e = blockIdx.x*256+threadIdx.x;
  if(e<E) atomicAdd(&counts[ei[E+e]],1);
}
__global__ void scan1(const int* __restrict__ counts, int* __restrict__ tmp,
                      int* __restrict__ bsums, int N){
  __shared__ int lds[256];
  int t = threadIdx.x; int idx = blockIdx.x*256+t;
  int v = (idx<N)? counts[idx]:0;
  lds[t]=v; __syncthreads();
  for(int off=1;off<256;off<<=1){
    int x = (t>=off)? lds[t-off]:0;
    __syncthreads();
    lds[t]+=x; __syncthreads();
  }
  if(idx<N) tmp[idx]=lds[t];
  if(t==255) bsums[blockIdx.x]=lds[255];
}
__global__ void scan2(const int* __restrict__ bsums, int* __restrict__ boffs, int nb){
  __shared__ int lds[256];
  int t=threadIdx.x;
  int v = (t<nb)? bsums[t]:0;
  lds[t]=v; __syncthreads();
  for(int off=1;off<256;off<<=1){
    int x=(t>=off)?lds[t-off]:0;
    __syncthreads();
    lds[t]+=x; __syncthreads();
  }
  if(t<nb) boffs[t] = lds[t]-v; // exclusive
}
__global__ void finalize_rs(const int* __restrict__ tmp, const int* __restrict__ boffs,
                            int* __restrict__ row_start, int N){
  int idx = blockIdx.x*256+threadIdx.x;
  if(idx<N) row_start[idx+1] = tmp[idx] + boffs[idx>>8];
  if(idx==0) row_start[0]=0;
}
// scatter original edge id into its node segment (order NON-deterministic here)
__global__ void csr_scatter(const int* __restrict__ ei, const int* __restrict__ rowst,
                            int* __restrict__ counts2, int* __restrict__ csr, int E){
  int e = blockIdx.x*256+threadIdx.x;
  if(e>=E) return;
  int d = ei[E+e];
  int p = rowst[d] + atomicAdd(&counts2[d],1);
  csr[p] = e;
}
// deterministic segment order: insertion-sort each node's edge ids ascending
__global__ void sort_seg(const int* __restrict__ rowst, int* __restrict__ csr, int N){
  int n = blockIdx.x*256+threadIdx.x;
  if(n>=N) return;
  int lo=rowst[n], hi=rowst[n+1];
  for(int i=lo+1;i<hi;i++){
    int v=csr[i]; int j=i-1;
    while(j>=lo && csr[j]>v){ csr[j+1]=csr[j]; j--; }
    csr[j+1]=v;
  }
}
// compute edge features per (sorted) slot
__global__ void edge_feat(const float* __restrict__ pos, const float* __restrict__ ew,
                          const int* __restrict__ ei, const int* __restrict__ csr,
                          float* __restrict__ efs, int* __restrict__ esrc, int E){
  int p = blockIdx.x*256 + threadIdx.x;
  if(p>=E) return;
  int e = csr[p];
  int s = ei[e], d = ei[E+e];
  float dx = pos[d*3+0]-pos[s*3+0];
  float dy = pos[d*3+1]-pos[s*3+1];
  float dz = pos[d*3+2]-pos[s*3+2];
  float D = sqrtf(dx*dx+dy*dy+dz*dz);
  float x = D*0.1f;
  float cut = 0.f;
  if(x < 1.f){ float x3=x*x*x, x4=x3*x, x5=x4*x; cut = 1.f - 6.f*x5 + 15.f*x4 - 10.f*x3; }
  float ed = expf(-D);
  const double e10 = 4.5399929762484854e-05; // exp(-10)
  const float step  = (float)((e10 - 1.0)/8.0);
  const float width = (float)((4.5/(1.0-e10))*(4.5/(1.0-e10)));
  float r12[12];
  #pragma unroll
  for(int k=0;k<KRBF;k++){
    float c = 1.0f + k*step;
    float dd = ed - c;
    r12[k] = cut*expf(-width*dd*dd);
  }
  r12[9] = ew[e]; r12[10]=0.f; r12[11]=0.f;
  float* o = efs + (size_t)p*12;
  *(float4*)&o[0] = *(float4*)&r12[0];
  *(float4*)&o[4] = *(float4*)&r12[4];
  *(float4*)&o[8] = *(float4*)&r12[8];
  esrc[p] = s;
}

// ---------------- degree-sorted node permutation (counting sort, 256 bins) ----------------
__global__ void deg_hist(const int* __restrict__ counts, int* __restrict__ dhist, int N){
  int n = blockIdx.x*256+threadIdx.x;
  if(n<N) atomicAdd(&dhist[min(counts[n],255)],1);
}
__global__ void deg_scan(const int* __restrict__ dhist, int* __restrict__ dstart){
  __shared__ int lds[256];
  int t=threadIdx.x;
  int v = dhist[t];
  lds[t]=v; __syncthreads();
  for(int off=1;off<256;off<<=1){
    int x=(t>=off)?lds[t-off]:0;
    __syncthreads();
    lds[t]+=x; __syncthreads();
  }
  dstart[t] = lds[t]-v; // exclusive
}
__global__ void deg_scatter(const int* __restrict__ counts, const int* __restrict__ dstart,
                            int* __restrict__ dcur, int* __restrict__ perm, int N){
  int n = blockIdx.x*256+threadIdx.x;
  if(n>=N) return;
  int d = min(counts[n],255);
  int p = dstart[d] + atomicAdd(&dcur[d],1);
  perm[p] = n;   // order within a bin nondeterministic, but per-node math is identical
}

// ---------------- weight packing: fp32 -> bf16, [col'][k], fragment-permuted ----------------
__global__ void pack_w(const float* __restrict__ Wq, const float* __restrict__ Wk,
                       const float* __restrict__ Wv, const float* __restrict__ Wsk,
                       const float* __restrict__ bq, const float* __restrict__ bk,
                       const float* __restrict__ bv, const float* __restrict__ bsk,
                       const float* __restrict__ We,
                       const float* __restrict__ W1, const float* __restrict__ W2,
                       const float* __restrict__ W3,
                       __hip_bfloat16* __restrict__ Wqkvs, float* __restrict__ bqkvs,
                       __hip_bfloat16* __restrict__ Wffn){
  int idx = blockIdx.x*256 + threadIdx.x;
  const int QT = NLAYER*QWCOLS*128;
  const int FT = NLAYER*3*128*128;
  const int BT = NLAYER*QWCOLS;
  if(idx < QT){
    int l = idx / (QWCOLS*128);
    int rem = idx - l*(QWCOLS*128);
    int colp = rem >> 7, k = rem & 127;
    int b = colp >> 7, p = colp & 127;
    int g = ((p&15)<<3) + (p>>4);
    int gcol = b*128 + g;
    float v = 0.f;
    if(gcol < 512){
      const float* src = (gcol<128)?Wq:((gcol<256)?Wk:((gcol<384)?Wv:Wsk));
      v = src[(size_t)l*16384 + k*128 + (gcol&127)];
    } else if(gcol < 552){
      int j = gcol-512; int h=j/10; int r=j-10*h;
      const float* wq = Wq + (size_t)l*16384 + k*128;
      const float* we = We + (size_t)l*1280 + r*128;
      float acc=0.f;
      #pragma unroll 8
      for(int c=32*h;c<32*h+32;c++) acc = fmaf(wq[c], we[c], acc);
      v = acc;
    }
    Wqkvs[idx] = __float2bfloat16(v);
  } else if(idx < QT+FT){
    int j = idx - QT;
    int k = j & 127; int colp = (j>>7)&127; int f = (j>>14)%3; int l = j/(3*16384);
    int g = ((colp&15)<<3) + (colp>>4);
    const float* src = (f==0)?W1:((f==1)?W2:W3);
    Wffn[j] = __float2bfloat16(src[(size_t)l*16384 + k*128 + g]);
  } else if(idx < QT+FT+BT){
    int j = idx - QT - FT;
    int l = j/QWCOLS; int col = j - l*QWCOLS;   // bias in NATURAL col order
    float v = 0.f;
    if(col<512){
      const float* src = (col<128)?bq:((col<256)?bk:((col<384)?bv:bsk));
      v = src[l*128 + (col&127)];
    } else if(col<552){
      int jj=col-512; int h=jj/10; int r=jj-10*h;
      const float* bqp = bq + l*128;
      const float* we = We + (size_t)l*1280 + r*128;
      float acc=0.f;
      for(int c=32*h;c<32*h+32;c++) acc = fmaf(bqp[c], we[c], acc);
      v = acc;
    }
    bqkvs[j] = v;
  }
}

// ---------------- LayerNorm (wave per node) fp32 -> bf16 (layer 0 only) ----------------
__global__ void ln_node(const float* __restrict__ h, const float* __restrict__ g,
                        const float* __restrict__ b, __hip_bfloat16* __restrict__ hn, int N){
  int n = blockIdx.x*4 + (threadIdx.x>>6);
  if(n>=N) return;
  int lane = threadIdx.x & 63;
  int c = 2*lane;
  float2 v = *(const float2*)&h[(size_t)n*HID + c];
  float s1 = wsum64(v.x+v.y);
  float s2 = wsum64(v.x*v.x+v.y*v.y);
  float mu = s1*(1.f/HID);
  float var = s2*(1.f/HID) - mu*mu;
  float rs = rsqrtf(var + 1e-5f);
  __hip_bfloat162 o;
  o.x = __float2bfloat16((v.x-mu)*rs*g[c]   + b[c]);
  o.y = __float2bfloat16((v.y-mu)*rs*g[c+1] + b[c+1]);
  *(__hip_bfloat162*)&hn[(size_t)n*HID + c] = o;
}

// ---------------- qkvs GEMM: 128 rows x 5 col-blocks, fragment-native ----------------
__global__ __launch_bounds__(256) void gemm_qkvs(
    const __hip_bfloat16* __restrict__ A, const __hip_bfloat16* __restrict__ Wt,
    const float* __restrict__ bias,
    __hip_bfloat16* __restrict__ qsO, __hip_bfloat16* __restrict__ kvO,
    float* __restrict__ qwO, int N){
  __shared__ __hip_bfloat16 Ws[128][WPAD];
  int row0 = blockIdx.y*128;
  int cb = blockIdx.x;
  int tid = threadIdx.x;
  {
    int chunk = tid&15, rbase = tid>>4;
    #pragma unroll
    for(int i=0;i<8;i++){
      int p = rbase + 16*i;
      *(float4*)&Ws[p][chunk*8] =
        *(const float4*)&Wt[(size_t)(cb*128+p)*128 + chunk*8];
    }
  }
  int lane = tid&63;
  int m0 = (tid>>6)*32;
  int ql = lane>>4, il = lane&15;
  bf16x8 af[2][4];
  #pragma unroll
  for(int mi=0;mi<2;mi++){
    int r = row0 + m0 + mi*16 + il;
    r = (r < N) ? r : (N-1);
    const __hip_bfloat16* ap = A + (size_t)r*128 + ql*8;
    #pragma unroll
    for(int kc=0;kc<4;kc++) af[mi][kc] = *(const bf16x8*)(ap + kc*32);
  }
  __syncthreads();
  f32x4 acc[2][8];
  #pragma unroll
  for(int mi=0;mi<2;mi++)
    #pragma unroll
    for(int nj=0;nj<8;nj++) acc[mi][nj] = (f32x4){0.f,0.f,0.f,0.f};
  #pragma unroll
  for(int kc=0;kc<4;kc++){
    #pragma unroll
    for(int nj=0;nj<8;nj++){
      bf16x8 bb = *(bf16x8*)&Ws[nj*16+il][kc*32+ql*8];
      #pragma unroll
      for(int mi=0;mi<2;mi++)
        acc[mi][nj] = __builtin_amdgcn_mfma_f32_16x16x32_bf16(af[mi][kc], bb, acc[mi][nj], 0,0,0);
    }
  }
  float bl8[8];
  {
    float4 b0 = *(const float4*)&bias[cb*128 + il*8];
    float4 b1 = *(const float4*)&bias[cb*128 + il*8 + 4];
    bl8[0]=b0.x; bl8[1]=b0.y; bl8[2]=b0.z; bl8[3]=b0.w;
    bl8[4]=b1.x; bl8[5]=b1.y; bl8[6]=b1.z; bl8[7]=b1.w;
  }
  #pragma unroll
  for(int mi=0;mi<2;mi++){
    #pragma unroll
    for(int r=0;r<4;r++){
      int rr = row0 + m0 + mi*16 + ql*4 + r;
      if(rr >= N) continue;
      if(cb < 4){
        bf16x8 o;
        #pragma unroll
        for(int nj=0;nj<8;nj++) o[nj] = f2bs(acc[mi][nj][r] + bl8[nj]);
        __hip_bfloat16* dst;
        if(cb==0)      dst = qsO + (size_t)rr*256 + il*8;          // q
        else if(cb==1) dst = kvO + (size_t)rr*256 + il*8;          // k
        else if(cb==2) dst = kvO + (size_t)rr*256 + 128 + il*8;    // v
        else           dst = qsO + (size_t)rr*256 + 128 + il*8;    // skip
        *(bf16x8*)dst = o;
      } else if(il < 5){
        #pragma unroll
        for(int nj=0;nj<8;nj++){
          int g = il*8 + nj;            // < 40
          int h = g/10, rb = g - 10*h;
          qwO[(size_t)rr*48 + h*12 + rb] = acc[mi][nj][r] + bl8[nj];
        }
      }
    }
  }
}

// ---------------- fused attention + beta-gate + residual + LN (v5) ----------------
// 4 nodes per wave: each 16-lane group owns one node (degree-sorted via perm),
// iterates its edges serially with 2-deep prefetch. No cross-group reduction;
// epilogue runs once per node per group. All lanes store 8 channels each.
__global__ __launch_bounds__(256) void attn_fused5(
    const __hip_bfloat16* __restrict__ qs, const __hip_bfloat16* __restrict__ kvb,
    const float* __restrict__ qwb, const float* __restrict__ efs,
    const int* __restrict__ esrc, const float* __restrict__ WeL,
    const int* __restrict__ rowst, const int* __restrict__ perm,
    const __hip_bfloat16* __restrict__ hn, const float* __restrict__ Wb,
    const float* __restrict__ lng, const float* __restrict__ lnb,
    __hip_bfloat16* __restrict__ hn2, int N){
  int j = blockIdx.x*16 + (threadIdx.x>>4);
  if(j>=N) return;
  int n = perm[j];
  int sl = threadIdx.x & 15;
  int c8 = sl*8, hd = sl>>2;
  const __hip_bfloat16* rowq = qs + (size_t)n*256;
  float q8[8];
  {
    bf16x8 qv = *(const bf16x8*)&rowq[c8];
    #pragma unroll
    for(int jj=0;jj<8;jj++) q8[jj] = b2f(qv[jj]);
  }
  const float* qwp = qwb + (size_t)n*48 + hd*12;
  float4 qa = *(const float4*)qwp;
  float4 qb = *(const float4*)(qwp+4);
  float2 qc = *(const float2*)(qwp+8);
  float QW[10] = {qa.x,qa.y,qa.z,qa.w,qb.x,qb.y,qb.z,qb.w,qc.x,qc.y};
  int lo = rowst[n], hi = rowst[n+1];
  float ssum = 0.f, a8[8], S[10];
  #pragma unroll
  for(int jj=0;jj<8;jj++) a8[jj]=0.f;
  #pragma unroll
  for(int r=0;r<10;r++) S[r]=0.f;
  int i = lo;
  if(i < hi){
    int s = esrc[i];
    const __hip_bfloat16* kr = kvb + (size_t)s*256;
    bf16x8 kc = *(const bf16x8*)&kr[c8];
    bf16x8 vc = *(const bf16x8*)&kr[128 + c8];
    const float* ef = efs + (size_t)i*12;
    float4 e0 = *(const float4*)&ef[0];
    float4 e1 = *(const float4*)&ef[4];
    float2 e2 = *(const float2*)&ef[8];
    while(true){
      int inext = i + 1;
      bool more = inext < hi;
      bf16x8 kn = kc, vn = vc;
      float4 f0 = e0, f1 = e1; float2 f2 = e2;
      if(more){
        int s2 = esrc[inext];
        const __hip_bfloat16* kr2 = kvb + (size_t)s2*256;
        kn = *(const bf16x8*)&kr2[c8];
        vn = *(const bf16x8*)&kr2[128 + c8];
        const float* ef2 = efs + (size_t)inext*12;
        f0 = *(const float4*)&ef2[0];
        f1 = *(const float4*)&ef2[4];
        f2 = *(const float2*)&ef2[8];
      }
      float d = 0.f;
      #pragma unroll
      for(int jj=0;jj<8;jj++) d = fmaf(q8[jj], b2f(kc[jj]), d);
      d += __shfl_xor(d,1,64); d += __shfl_xor(d,2,64);   // 32-ch head dot (quad)
      float lg = d;
      lg = fmaf(e0.x,QW[0],lg); lg = fmaf(e0.y,QW[1],lg);
      lg = fmaf(e0.z,QW[2],lg); lg = fmaf(e0.w,QW[3],lg);
      lg = fmaf(e1.x,QW[4],lg); lg = fmaf(e1.y,QW[5],lg);
      lg = fmaf(e1.z,QW[6],lg); lg = fmaf(e1.w,QW[7],lg);
      lg = fmaf(e2.x,QW[8],lg); lg = fmaf(e2.y,QW[9],lg);
      lg *= 0.17677669529663687f;
      lg = fminf(lg, 80.f);
      float w = __expf(lg);
      ssum += w;
      #pragma unroll
      for(int jj=0;jj<8;jj++) a8[jj] = fmaf(w, b2f(vc[jj]), a8[jj]);
      S[0]=fmaf(w,e0.x,S[0]); S[1]=fmaf(w,e0.y,S[1]); S[2]=fmaf(w,e0.z,S[2]);
      S[3]=fmaf(w,e0.w,S[3]); S[4]=fmaf(w,e1.x,S[4]); S[5]=fmaf(w,e1.y,S[5]);
      S[6]=fmaf(w,e1.z,S[6]); S[7]=fmaf(w,e1.w,S[7]); S[8]=fmaf(w,e2.x,S[8]);
      S[9]=fmaf(w,e2.y,S[9]);
      if(!more) break;
      kc = kn; vc = vn; e0 = f0; e1 = f1; e2 = f2;
      i = inext;
    }
  }
  // ---- epilogue: out -> beta gate -> residual softplus -> LayerNorm ----
  float inv = (hi>lo)? 1.f/ssum : 0.f;
  float o8[8];
  #pragma unroll
  for(int jj=0;jj<8;jj++) o8[jj]=a8[jj];
  #pragma unroll
  for(int r=0;r<10;r++){
    float s=S[r];
    float4 wa = *(const float4*)&WeL[r*128+c8];
    float4 wb = *(const float4*)&WeL[r*128+c8+4];
    o8[0]=fmaf(s,wa.x,o8[0]); o8[1]=fmaf(s,wa.y,o8[1]);
    o8[2]=fmaf(s,wa.z,o8[2]); o8[3]=fmaf(s,wa.w,o8[3]);
    o8[4]=fmaf(s,wb.x,o8[4]); o8[5]=fmaf(s,wb.y,o8[5]);
    o8[6]=fmaf(s,wb.z,o8[6]); o8[7]=fmaf(s,wb.w,o8[7]);
  }
  #pragma unroll
  for(int jj=0;jj<8;jj++) o8[jj] *= inv;
  float xr8[8];
  {
    bf16x8 xv = *(const bf16x8*)&rowq[128 + c8];
    #pragma unroll
    for(int jj=0;jj<8;jj++) xr8[jj] = b2f(xv[jj]);
  }
  float pb = 0.f;
  {
    float4 a0=*(const float4*)&Wb[c8],     a1=*(const float4*)&Wb[c8+4];
    float4 b0=*(const float4*)&Wb[128+c8], b1=*(const float4*)&Wb[128+c8+4];
    float4 c0=*(const float4*)&Wb[256+c8], c1=*(const float4*)&Wb[256+c8+4];
    float wb0[8]={a0.x,a0.y,a0.z,a0.w,a1.x,a1.y,a1.z,a1.w};
    float wb1[8]={b0.x,b0.y,b0.z,b0.w,b1.x,b1.y,b1.z,b1.w};
    float wb2[8]={c0.x,c0.y,c0.z,c0.w,c1.x,c1.y,c1.z,c1.w};
    #pragma unroll
    for(int jj=0;jj<8;jj++)
      pb += o8[jj]*wb0[jj] + xr8[jj]*wb1[jj] + (o8[jj]-xr8[jj])*wb2[jj];
  }
  pb = wsum16(pb);
  float beta = sigm_(pb);
  float h8[8], s1=0.f, s2=0.f;
  {
    bf16x8 hv = *(const bf16x8*)&hn[(size_t)n*128 + c8];
    #pragma unroll
    for(int jj=0;jj<8;jj++){
      float u = beta*xr8[jj] + (1.f-beta)*o8[jj];
      float x = b2f(hv[jj]) + sp_(u);
      h8[jj]=x; s1+=x; s2+=x*x;
    }
  }
  s1 = wsum16(s1); s2 = wsum16(s2);
  float mu = s1*(1.f/128.f);
  float var = s2*(1.f/128.f) - mu*mu;
  float rsg = rsqrtf(var + 1e-5f);
  {
    float4 g0=*(const float4*)&lng[c8], g1=*(const float4*)&lng[c8+4];
    float4 bb0=*(const float4*)&lnb[c8], bb1=*(const float4*)&lnb[c8+4];
    float g8[8]={g0.x,g0.y,g0.z,g0.w,g1.x,g1.y,g1.z,g1.w};
    float lb8[8]={bb0.x,bb0.y,bb0.z,bb0.w,bb1.x,bb1.y,bb1.z,bb1.w};
    bf16x8 o;
    #pragma unroll
    for(int jj=0;jj<8;jj++) o[jj] = f2bs((h8[jj]-mu)*rsg*g8[jj] + lb8[jj]);
    *(bf16x8*)&hn2[(size_t)n*128 + c8] = o;
  }
}

// ---------------- fused FFN: 3 chained GEMMs, LDS intermediates ----------------
__global__ __launch_bounds__(256) void ffn_fused(
    const __hip_bfloat16* __restrict__ hn2, const __hip_bfloat16* __restrict__ Wf,
    const float* __restrict__ b1, const float* __restrict__ b2,
    const float* __restrict__ b3, const float* __restrict__ lng,
    const float* __restrict__ lnb, float* __restrict__ hout,
    __hip_bfloat16* __restrict__ hnout, int N){
  __shared__ __hip_bfloat16 Ws[128][WPAD];
  __shared__ __hip_bfloat16 inter[2][64][WPAD];
  int row0 = blockIdx.x*64;
  int tid = threadIdx.x, lane = tid&63, wv = tid>>6;
  int ql = lane>>4, il = lane&15;
  int chunk = tid&15, rbase = tid>>4;

  auto stage = [&](const __hip_bfloat16* Wp){
    #pragma unroll
    for(int i=0;i<8;i++){
      int p = rbase + 16*i;
      *(float4*)&Ws[p][chunk*8] = *(const float4*)&Wp[(size_t)p*128 + chunk*8];
    }
  };
  auto loadbias = [&](const float* bp, float* bl8){
    float4 x0 = *(const float4*)&bp[il*8];
    float4 x1 = *(const float4*)&bp[il*8+4];
    bl8[0]=x0.x; bl8[1]=x0.y; bl8[2]=x0.z; bl8[3]=x0.w;
    bl8[4]=x1.x; bl8[5]=x1.y; bl8[6]=x1.z; bl8[7]=x1.w;
  };

  f32x4 acc[8];
  bf16x8 af[4];
  // ---- FFN1 (A from global) ----
  stage(Wf);
  {
    int r = row0 + wv*16 + il;
    r = (r<N)? r : (N-1);
    const __hip_bfloat16* ap = hn2 + (size_t)r*128 + ql*8;
    #pragma unroll
    for(int kc=0;kc<4;kc++) af[kc] = *(const bf16x8*)(ap + kc*32);
  }
  __syncthreads();
  #pragma unroll
  for(int nj=0;nj<8;nj++) acc[nj] = (f32x4){0.f,0.f,0.f,0.f};
  #pragma unroll
  for(int kc=0;kc<4;kc++)
    #pragma unroll
    for(int nj=0;nj<8;nj++){
      bf16x8 bb = *(bf16x8*)&Ws[nj*16+il][kc*32+ql*8];
      acc[nj] = __builtin_amdgcn_mfma_f32_16x16x32_bf16(af[kc], bb, acc[nj], 0,0,0);
    }
  {
    float bl8[8]; loadbias(b1, bl8);
    #pragma unroll
    for(int r=0;r<4;r++){
      int lr = wv*16 + ql*4 + r;
      bf16x8 o;
      #pragma unroll
      for(int nj=0;nj<8;nj++) o[nj] = f2bs(sp_(acc[nj][r] + bl8[nj]));
      *(bf16x8*)&inter[0][lr][il*8] = o;
    }
  }
  __syncthreads();
  // ---- FFN2 (A from inter[0]) ----
  stage(Wf + 16384);
  #pragma unroll
  for(int kc=0;kc<4;kc++) af[kc] = *(bf16x8*)&inter[0][wv*16+il][ql*8 + kc*32];
  __syncthreads();
  #pragma unroll
  for(int nj=0;nj<8;nj++) acc[nj] = (f32x4){0.f,0.f,0.f,0.f};
  #pragma unroll
  for(int kc=0;kc<4;kc++)
    #pragma unroll
    for(int nj=0;nj<8;nj++){
      bf16x8 bb = *(bf16x8*)&Ws[nj*16+il][kc*32+ql*8];
      acc[nj] = __builtin_amdgcn_mfma_f32_16x16x32_bf16(af[kc], bb, acc[nj], 0,0,0);
    }
  {
    float bl8[8]; loadbias(b2, bl8);
    #pragma unroll
    for(int r=0;r<4;r++){
      int lr = wv*16 + ql*4 + r;
      bf16x8 o;
      #pragma unroll
      for(int nj=0;nj<8;nj++) o[nj] = f2bs(sp_(acc[nj][r] + bl8[nj]));
      *(bf16x8*)&inter[1][lr][il*8] = o;
    }
  }
  __syncthreads();
  // ---- FFN3 (A from inter[1]) + epilogue ----
  stage(Wf + 2*16384);
  #pragma unroll
  for(int kc=0;kc<4;kc++) af[kc] = *(bf16x8*)&inter[1][wv*16+il][ql*8 + kc*32];
  __syncthreads();
  #pragma unroll
  for(int nj=0;nj<8;nj++) acc[nj] = (f32x4){0.f,0.f,0.f,0.f};
  #pragma unroll
  for(int kc=0;kc<4;kc++)
    #pragma unroll
    for(int nj=0;nj<8;nj++){
      bf16x8 bb = *(bf16x8*)&Ws[nj*16+il][kc*32+ql*8];
      acc[nj] = __builtin_amdgcn_mfma_f32_16x16x32_bf16(af[kc], bb, acc[nj], 0,0,0);
    }
  {
    float bl8[8]; loadbias(b3, bl8);
    float lg8[8], lb8[8];
    loadbias(lng, lg8); loadbias(lnb, lb8);
    #pragma unroll
    for(int r=0;r<4;r++){
      int rr = row0 + wv*16 + ql*4 + r;
      if(rr >= N) continue;     // uniform across il -> shfl-safe
      bf16x8 rv = *(const bf16x8*)&hn2[(size_t)rr*128 + il*8];
      float t8[8], s1=0.f, s2=0.f;
      #pragma unroll
      for(int nj=0;nj<8;nj++){
        float x = sp_(acc[nj][r] + bl8[nj]) + b2f(rv[nj]);
        t8[nj]=x; s1+=x; s2+=x*x;
      }
      s1 = wsum16(s1); s2 = wsum16(s2);
      float mu = s1*(1.f/128.f);
      float var = s2*(1.f/128.f) - mu*mu;
      float rsg = rsqrtf(var + 1e-5f);
      *(float4*)&hout[(size_t)rr*128 + il*8]     = make_float4(t8[0],t8[1],t8[2],t8[3]);
      *(float4*)&hout[(size_t)rr*128 + il*8 + 4] = make_float4(t8[4],t8[5],t8[6],t8[7]);
      bf16x8 o;
      #pragma unroll
      for(int nj=0;nj<8;nj++) o[nj] = f2bs((t8[nj]-mu)*rsg*lg8[nj] + lb8[nj]);
      *(bf16x8*)&hnout[(size_t)rr*128 + il*8] = o;
    }
  }
}

// ---------------- pooling + output head (block per graph) ----------------
__global__ void pool_head(const float* __restrict__ h, const int* __restrict__ batch,
                          const float* __restrict__ Wo1, const float* __restrict__ bo1,
                          const float* __restrict__ Wo2, const float* __restrict__ bo2,
                          float* __restrict__ out, int N){
  int gid = blockIdx.x;
  int t = threadIdx.x;  // 128 threads
  int lo = lb_(batch, N, gid), hi = lb_(batch, N, gid+1);
  __shared__ float pl[128];
  __shared__ float red[128];
  float s = 0.f;
  for(int i=lo;i<hi;i++) s += h[(size_t)i*HID + t];
  pl[t] = s;
  __syncthreads();
  float acc = bo1[t];
  for(int c=0;c<128;c++) acc = fmaf(pl[c], Wo1[c*HID+t], acc);
  red[t] = sp_(acc)*Wo2[t];
  __syncthreads();
  for(int off=64;off>0;off>>=1){
    if(t<off) red[t]+=red[t+off];
    __syncthreads();
  }
  if(t==0) out[gid] = red[0] + bo2[0];
}

extern "C" void kernel_launch(void* const* d_in, const int* in_sizes, int n_in,
                              void* d_out, int out_size, void* d_ws, size_t ws_size,
                              hipStream_t stream){
  const float* h_in = (const float*)d_in[0];
  const float* pos  = (const float*)d_in[1];
  const float* ew   = (const float*)d_in[2];
  const float* Wq = (const float*)d_in[3];  const float* bq = (const float*)d_in[4];
  const float* Wk = (const float*)d_in[5];  const float* bk = (const float*)d_in[6];
  const float* Wv = (const float*)d_in[7];  const float* bv = (const float*)d_in[8];
  const float* We = (const float*)d_in[9];
  const float* Wsk= (const float*)d_in[10]; const float* bsk=(const float*)d_in[11];
  const float* Wbeta=(const float*)d_in[12];
  const float* W1=(const float*)d_in[13]; const float* b1=(const float*)d_in[14];
  const float* W2=(const float*)d_in[15]; const float* b2=(const float*)d_in[16];
  const float* W3=(const float*)d_in[17]; const float* b3=(const float*)d_in[18];
  const float* lng=(const float*)d_in[19]; const float* lnb=(const float*)d_in[20];
  const float* Wo1=(const float*)d_in[21]; const float* bo1=(const float*)d_in[22];
  const float* Wo2=(const float*)d_in[23]; const float* bo2=(const float*)d_in[24];
  const int* ei    = (const int*)d_in[25];
  const int* batch = (const int*)d_in[26];
  int N = in_sizes[0]/HID;
  int E = in_sizes[2];
  int G = out_size;
  float* out = (float*)d_out;

  char* ws = (char*)d_ws;
  size_t off=0;
  auto alloc=[&](size_t bytes)->char*{
    char* p = ws + off;
    off = (off + bytes + 255) & ~(size_t)255;
    return p;
  };
  float* efs   =(float*)alloc((size_t)E*12*4);
  int* esrc    =(int*)  alloc((size_t)E*4);
  int* csr     =(int*)  alloc((size_t)E*4);
  int* counts  =(int*)  alloc((size_t)N*4);
  int* counts2 =(int*)  alloc((size_t)N*4);
  int* rowst   =(int*)  alloc((size_t)(N+1)*4);
  int* tmp     =(int*)  alloc((size_t)N*4);
  int* bsums   =(int*)  alloc(256*4);
  int* boffs   =(int*)  alloc(256*4);
  int* perm    =(int*)  alloc((size_t)N*4);
  int* dhist   =(int*)  alloc(256*4);
  int* dstart  =(int*)  alloc(256*4);
  int* dcur    =(int*)  alloc(256*4);
  __hip_bfloat16* hn   =(__hip_bfloat16*)alloc((size_t)N*HID*2);
  __hip_bfloat16* hn2  =(__hip_bfloat16*)alloc((size_t)N*HID*2);
  __hip_bfloat16* qsb  =(__hip_bfloat16*)alloc((size_t)N*256*2);
  __hip_bfloat16* kvb  =(__hip_bfloat16*)alloc((size_t)N*256*2);
  float* qwb   =(float*)alloc((size_t)N*48*4);
  float* hcur  =(float*)alloc((size_t)N*HID*4);
  __hip_bfloat16* Wqkvs_t =(__hip_bfloat16*)alloc((size_t)NLAYER*QWCOLS*128*2);
  __hip_bfloat16* Wffn_t  =(__hip_bfloat16*)alloc((size_t)NLAYER*3*128*128*2);
  float* bqkvs =(float*)alloc((size_t)NLAYER*QWCOLS*4);

  int ebl = (E+255)/256;
  int nb  = (N+255)/256;
  int nwb = (N+3)/4;
  int ngb = (N+15)/16;
  int nrb128 = (N+127)/128;
  int nrb64  = (N+63)/64;
  dim3 gqkvs(QWCOLS/128, nrb128);   // 5 x 391

  hipMemsetAsync(counts, 0, (size_t)N*4, stream);
  hipMemsetAsync(counts2,0, (size_t)N*4, stream);
  hipMemsetAsync(dhist,  0, 256*4, stream);
  hipMemsetAsync(dcur,   0, 256*4, stream);
  count_dst<<<ebl,256,0,stream>>>(ei,counts,E);
  scan1<<<nb,256,0,stream>>>(counts,tmp,bsums,N);
  scan2<<<1,256,0,stream>>>(bsums,boffs,nb);
  finalize_rs<<<nb,256,0,stream>>>(tmp,boffs,rowst,N);
  csr_scatter<<<ebl,256,0,stream>>>(ei,rowst,counts2,csr,E);
  sort_seg<<<nb,256,0,stream>>>(rowst,csr,N);          // deterministic order
  edge_feat<<<ebl,256,0,stream>>>(pos,ew,ei,csr,efs,esrc,E);
  deg_hist<<<nb,256,0,stream>>>(counts,dhist,N);
  deg_scan<<<1,256,0,stream>>>(dhist,dstart);
  deg_scatter<<<nb,256,0,stream>>>(counts,dstart,dcur,perm,N);
  {
    int tot = NLAYER*QWCOLS*128 + NLAYER*3*128*128 + NLAYER*QWCOLS;
    pack_w<<<(tot+255)/256,256,0,stream>>>(Wq,Wk,Wv,Wsk,bq,bk,bv,bsk,We,W1,W2,W3,
                                           Wqkvs_t,bqkvs,Wffn_t);
  }

  ln_node<<<nwb,256,0,stream>>>(h_in,lng,lnb,hn,N);
  for(int l=0;l<NLAYER;l++){
    const float* We_l = We + (size_t)l*(KRBF+1)*HID;
    const float* Wb_l = Wbeta + (size_t)l*3*HID;
    const float* b1_l = b1 + (size_t)l*HID;
    const float* b2_l = b2 + (size_t)l*HID;
    const float* b3_l = b3 + (size_t)l*HID;

    gemm_qkvs<<<gqkvs,256,0,stream>>>(hn, Wqkvs_t + (size_t)l*QWCOLS*128,
                                      bqkvs + l*QWCOLS, qsb, kvb, qwb, N);
    attn_fused5<<<ngb,256,0,stream>>>(qsb,kvb,qwb,efs,esrc,We_l,rowst,perm,hn,
                                      Wb_l,lng,lnb,hn2,N);
    ffn_fused<<<nrb64,256,0,stream>>>(hn2, Wffn_t + (size_t)l*3*16384,
                                      b1_l,b2_l,b3_l,lng,lnb,hcur,hn,N);
  }
  pool_head<<<G,128,0,stream>>>(hcur,batch,Wo1,bo1,Wo2,bo2,out,N);
}

// Round 9
// 926.657 us; speedup vs baseline: 1.7042x; 1.7042x over previous
//
#include <hip/hip_runtime.h>
#include <hip/hip_bf16.h>
#include <math.h>

#define HID 128
#define KRBF 9
#define NLAYER 3
#define IPAD 136    // inter LDS row stride (halfwords): 272B -> all rows 16B-aligned

typedef __attribute__((ext_vector_type(8))) short bf16x8;
typedef __attribute__((ext_vector_type(4))) float f32x4;

__device__ __forceinline__ float sp_(float x){ return fmaxf(x,0.f) + log1pf(expf(-fabsf(x))); }
__device__ __forceinline__ float sigm_(float x){ return 1.f/(1.f+expf(-x)); }
__device__ __forceinline__ float b2f(short s){
  union{unsigned u; float f;} x; x.u = ((unsigned)(unsigned short)s)<<16; return x.f;
}
__device__ __forceinline__ short f2bs(float x){
  __hip_bfloat16 b = __float2bfloat16(x);
  return *reinterpret_cast<short*>(&b);
}
__device__ __forceinline__ float wsum64(float v){
  #pragma unroll
  for(int m=1;m<64;m<<=1) v += __shfl_xor(v,m,64);
  return v;
}
__device__ __forceinline__ float wsum16(float v){
  #pragma unroll
  for(int m=1;m<16;m<<=1) v += __shfl_xor(v,m,64);
  return v;
}
__device__ __forceinline__ int lb_(const int* __restrict__ a, int n, int key){
  int lo=0, hi=n;
  while(lo<hi){ int mid=(lo+hi)>>1; if(a[mid]<key) lo=mid+1; else hi=mid; }
  return lo;
}

// ---------------- CSR ----------------
__global__ void count_dst(const int* __restrict__ ei, int* __restrict__ counts, int E){
  int e = blockIdx.x*256+threadIdx.x;
  if(e<E) atomicAdd(&counts[ei[E+e]],1);
}
__global__ void scan1(const int* __restrict__ counts, int* __restrict__ tmp,
                      int* __restrict__ bsums, int N){
  __shared__ int lds[256];
  int t = threadIdx.x; int idx = blockIdx.x*256+t;
  int v = (idx<N)? counts[idx]:0;
  lds[t]=v; __syncthreads();
  for(int off=1;off<256;off<<=1){
    int x = (t>=off)? lds[t-off]:0;
    __syncthreads();
    lds[t]+=x; __syncthreads();
  }
  if(idx<N) tmp[idx]=lds[t];
  if(t==255) bsums[blockIdx.x]=lds[255];
}
__global__ void scan2(const int* __restrict__ bsums, int* __restrict__ boffs, int nb){
  __shared__ int lds[256];
  int t=threadIdx.x;
  int v = (t<nb)? bsums[t]:0;
  lds[t]=v; __syncthreads();
  for(int off=1;off<256;off<<=1){
    int x=(t>=off)?lds[t-off]:0;
    __syncthreads();
    lds[t]+=x; __syncthreads();
  }
  if(t<nb) boffs[t] = lds[t]-v; // exclusive
}
__global__ void finalize_rs(const int* __restrict__ tmp, const int* __restrict__ boffs,
                            int* __restrict__ row_start, int N){
  int idx = blockIdx.x*256+threadIdx.x;
  if(idx<N) row_start[idx+1] = tmp[idx] + boffs[idx>>8];
  if(idx==0) row_start[0]=0;
}
__global__ void csr_scatter(const int* __restrict__ ei, const int* __restrict__ rowst,
                            int* __restrict__ counts2, int* __restrict__ csr, int E){
  int e = blockIdx.x*256+threadIdx.x;
  if(e>=E) return;
  int d = ei[E+e];
  int p = rowst[d] + atomicAdd(&counts2[d],1);
  csr[p] = e;
}
// deterministic segment order: insertion-sort each node's edge ids ascending
__global__ void sort_seg(const int* __restrict__ rowst, int* __restrict__ csr, int N){
  int n = blockIdx.x*256+threadIdx.x;
  if(n>=N) return;
  int lo=rowst[n], hi=rowst[n+1];
  for(int i=lo+1;i<hi;i++){
    int v=csr[i]; int j=i-1;
    while(j>=lo && csr[j]>v){ csr[j+1]=csr[j]; j--; }
    csr[j+1]=v;
  }
}
__global__ void edge_feat(const float* __restrict__ pos, const float* __restrict__ ew,
                          const int* __restrict__ ei, const int* __restrict__ csr,
                          float* __restrict__ efs, int* __restrict__ esrc, int E){
  int p = blockIdx.x*256 + threadIdx.x;
  if(p>=E) return;
  int e = csr[p];
  int s = ei[e], d = ei[E+e];
  float dx = pos[d*3+0]-pos[s*3+0];
  float dy = pos[d*3+1]-pos[s*3+1];
  float dz = pos[d*3+2]-pos[s*3+2];
  float D = sqrtf(dx*dx+dy*dy+dz*dz);
  float x = D*0.1f;
  float cut = 0.f;
  if(x < 1.f){ float x3=x*x*x, x4=x3*x, x5=x4*x; cut = 1.f - 6.f*x5 + 15.f*x4 - 10.f*x3; }
  float ed = expf(-D);
  const double e10 = 4.5399929762484854e-05; // exp(-10)
  const float step  = (float)((e10 - 1.0)/8.0);
  const float width = (float)((4.5/(1.0-e10))*(4.5/(1.0-e10)));
  float r12[12];
  #pragma unroll
  for(int k=0;k<KRBF;k++){
    float c = 1.0f + k*step;
    float dd = ed - c;
    r12[k] = cut*expf(-width*dd*dd);
  }
  r12[9] = ew[e]; r12[10]=0.f; r12[11]=0.f;
  float* o = efs + (size_t)p*12;
  *(float4*)&o[0] = *(float4*)&r12[0];
  *(float4*)&o[4] = *(float4*)&r12[4];
  *(float4*)&o[8] = *(float4*)&r12[8];
  esrc[p] = s;
}

// ---------------- weight packing: MFMA fragment-flat order ----------------
// Per 128-col block: element index ((kc*8+nj)*64 + ql*16 + il)*8 + j holds
// W[k = kc*32+ql*8+j][gcol = il*8+nj]. Staging = pure linear copy; LDS reads
// are lane*16B contiguous -> zero bank conflicts.
__global__ void pack_w(const float* __restrict__ Wq, const float* __restrict__ Wk,
                       const float* __restrict__ Wv, const float* __restrict__ Wsk,
                       const float* __restrict__ bq, const float* __restrict__ bk,
                       const float* __restrict__ bv, const float* __restrict__ bsk,
                       const float* __restrict__ We,
                       const float* __restrict__ W1, const float* __restrict__ W2,
                       const float* __restrict__ W3,
                       __hip_bfloat16* __restrict__ Wqkvs, float* __restrict__ bqkvs,
                       __hip_bfloat16* __restrict__ Wffn){
  int idx = blockIdx.x*256 + threadIdx.x;
  const int QT = NLAYER*5*16384;
  const int FT = NLAYER*3*16384;
  const int BT = NLAYER*640;
  if(idx < QT){
    int l = idx / (5*16384);
    int rem = idx - l*(5*16384);
    int cb = rem >> 14;
    int t = rem & 16383;
    int j = t&7; int lane = (t>>3)&63; int blk = t>>9;
    int kc = blk>>3, nj = blk&7, ql = lane>>4, il = lane&15;
    int k = kc*32 + ql*8 + j;
    int gcol = cb*128 + il*8 + nj;
    float v = 0.f;
    if(gcol < 512){
      const float* src = (gcol<128)?Wq:((gcol<256)?Wk:((gcol<384)?Wv:Wsk));
      v = src[(size_t)l*16384 + k*128 + (gcol&127)];
    } else if(gcol < 552){
      int jj = gcol-512; int h=jj/10; int r=jj-10*h;
      const float* wq = Wq + (size_t)l*16384 + k*128;
      const float* we = We + (size_t)l*1280 + r*128;
      float acc=0.f;
      #pragma unroll 8
      for(int c=32*h;c<32*h+32;c++) acc = fmaf(wq[c], we[c], acc);
      v = acc;
    }
    Wqkvs[idx] = __float2bfloat16(v);
  } else if(idx < QT+FT){
    int r0 = idx - QT;
    int l = r0 / (3*16384);
    int rem = r0 - l*(3*16384);
    int f = rem >> 14;
    int t = rem & 16383;
    int j = t&7; int lane = (t>>3)&63; int blk = t>>9;
    int kc = blk>>3, nj = blk&7, ql = lane>>4, il = lane&15;
    int k = kc*32 + ql*8 + j;
    int gcol = il*8 + nj;
    const float* src = (f==0)?W1:((f==1)?W2:W3);
    Wffn[r0] = __float2bfloat16(src[(size_t)l*16384 + k*128 + gcol]);
  } else if(idx < QT+FT+BT){
    int j = idx - QT - FT;
    int l = j/640; int col = j - l*640;   // bias in NATURAL col order
    float v = 0.f;
    if(col<512){
      const float* src = (col<128)?bq:((col<256)?bk:((col<384)?bv:bsk));
      v = src[l*128 + (col&127)];
    } else if(col<552){
      int jj=col-512; int h=jj/10; int r=jj-10*h;
      const float* bqp = bq + l*128;
      const float* we = We + (size_t)l*1280 + r*128;
      float acc=0.f;
      for(int c=32*h;c<32*h+32;c++) acc = fmaf(bqp[c], we[c], acc);
      v = acc;
    }
    bqkvs[j] = v;
  }
}

// ---------------- LayerNorm (wave per node) fp32 -> bf16 (layer 0 only) ----------------
__global__ void ln_node(const float* __restrict__ h, const float* __restrict__ g,
                        const float* __restrict__ b, __hip_bfloat16* __restrict__ hn, int N){
  int n = blockIdx.x*4 + (threadIdx.x>>6);
  if(n>=N) return;
  int lane = threadIdx.x & 63;
  int c = 2*lane;
  float2 v = *(const float2*)&h[(size_t)n*HID + c];
  float s1 = wsum64(v.x+v.y);
  float s2 = wsum64(v.x*v.x+v.y*v.y);
  float mu = s1*(1.f/HID);
  float var = s2*(1.f/HID) - mu*mu;
  float rs = rsqrtf(var + 1e-5f);
  __hip_bfloat162 o;
  o.x = __float2bfloat16((v.x-mu)*rs*g[c]   + b[c]);
  o.y = __float2bfloat16((v.y-mu)*rs*g[c+1] + b[c+1]);
  *(__hip_bfloat162*)&hn[(size_t)n*HID + c] = o;
}

// ---------------- qkvs GEMM: 128 rows x 5 col-blocks, fragment-flat LDS ----------------
__global__ __launch_bounds__(256) void gemm_qkvs(
    const __hip_bfloat16* __restrict__ A, const __hip_bfloat16* __restrict__ Wt,
    const float* __restrict__ bias,
    __hip_bfloat16* __restrict__ qsO, __hip_bfloat16* __restrict__ kvO,
    float* __restrict__ qwO, int N){
  __shared__ __hip_bfloat16 WsF[16384];
  int row0 = blockIdx.y*128;
  int cb = blockIdx.x;
  int tid = threadIdx.x;
  {
    const __hip_bfloat16* Wp = Wt + (size_t)cb*16384;
    #pragma unroll
    for(int i=0;i<8;i++){
      int o = (tid + 256*i)*8;
      *(float4*)&WsF[o] = *(const float4*)&Wp[o];
    }
  }
  int lane = tid&63;
  int m0 = (tid>>6)*32;
  int ql = lane>>4, il = lane&15;
  bf16x8 af[2][4];
  #pragma unroll
  for(int mi=0;mi<2;mi++){
    int r = row0 + m0 + mi*16 + il;
    r = (r < N) ? r : (N-1);
    const __hip_bfloat16* ap = A + (size_t)r*128 + ql*8;
    #pragma unroll
    for(int kc=0;kc<4;kc++) af[mi][kc] = *(const bf16x8*)(ap + kc*32);
  }
  __syncthreads();
  f32x4 acc[2][8];
  #pragma unroll
  for(int mi=0;mi<2;mi++)
    #pragma unroll
    for(int nj=0;nj<8;nj++) acc[mi][nj] = (f32x4){0.f,0.f,0.f,0.f};
  #pragma unroll
  for(int kc=0;kc<4;kc++){
    #pragma unroll
    for(int nj=0;nj<8;nj++){
      bf16x8 bb = *(bf16x8*)&WsF[((kc*8+nj)*64 + lane)*8];
      #pragma unroll
      for(int mi=0;mi<2;mi++)
        acc[mi][nj] = __builtin_amdgcn_mfma_f32_16x16x32_bf16(af[mi][kc], bb, acc[mi][nj], 0,0,0);
    }
  }
  float bl8[8];
  {
    float4 b0 = *(const float4*)&bias[cb*128 + il*8];
    float4 b1 = *(const float4*)&bias[cb*128 + il*8 + 4];
    bl8[0]=b0.x; bl8[1]=b0.y; bl8[2]=b0.z; bl8[3]=b0.w;
    bl8[4]=b1.x; bl8[5]=b1.y; bl8[6]=b1.z; bl8[7]=b1.w;
  }
  #pragma unroll
  for(int mi=0;mi<2;mi++){
    #pragma unroll
    for(int r=0;r<4;r++){
      int rr = row0 + m0 + mi*16 + ql*4 + r;
      if(rr >= N) continue;
      if(cb < 4){
        bf16x8 o;
        #pragma unroll
        for(int nj=0;nj<8;nj++) o[nj] = f2bs(acc[mi][nj][r] + bl8[nj]);
        __hip_bfloat16* dst;
        if(cb==0)      dst = qsO + (size_t)rr*256 + il*8;          // q
        else if(cb==1) dst = kvO + (size_t)rr*256 + il*8;          // k
        else if(cb==2) dst = kvO + (size_t)rr*256 + 128 + il*8;    // v
        else           dst = qsO + (size_t)rr*256 + 128 + il*8;    // skip
        *(bf16x8*)dst = o;
      } else if(il < 5){
        #pragma unroll
        for(int nj=0;nj<8;nj++){
          int g = il*8 + nj;            // < 40
          int h = g/10, rb = g - 10*h;
          qwO[(size_t)rr*48 + h*12 + rb] = acc[mi][nj][r] + bl8[nj];
        }
      }
    }
  }
}

// ---------------- fused attention + beta-gate + residual + LN (v4b) ----------------
// wave per node: 4 edges/wave (eg), 16 lanes/edge, 8 ch/lane; 2-deep prefetch.
// We-fold applied per-eg BEFORE the cross-eg reduce (9 values instead of 19).
__global__ __launch_bounds__(256) void attn_fused4(
    const __hip_bfloat16* __restrict__ qs, const __hip_bfloat16* __restrict__ kvb,
    const float* __restrict__ qwb, const float* __restrict__ efs,
    const int* __restrict__ esrc, const float* __restrict__ WeL,
    const int* __restrict__ rowst, const __hip_bfloat16* __restrict__ hn,
    const float* __restrict__ Wb, const float* __restrict__ lng,
    const float* __restrict__ lnb, __hip_bfloat16* __restrict__ hn2, int N){
  int n = blockIdx.x*4 + (threadIdx.x>>6);
  if(n>=N) return;
  int lane = threadIdx.x & 63;
  int eg = lane>>4, sl = lane&15;
  int c8 = sl*8, hd = sl>>2;
  const __hip_bfloat16* rowq = qs + (size_t)n*256;
  float q8[8];
  {
    bf16x8 qv = *(const bf16x8*)&rowq[c8];
    #pragma unroll
    for(int j=0;j<8;j++) q8[j] = b2f(qv[j]);
  }
  const float* qwp = qwb + (size_t)n*48 + hd*12;
  float4 qa = *(const float4*)qwp;
  float4 qb = *(const float4*)(qwp+4);
  float2 qc = *(const float2*)(qwp+8);
  float QW[10] = {qa.x,qa.y,qa.z,qa.w,qb.x,qb.y,qb.z,qb.w,qc.x,qc.y};
  int lo = rowst[n], hi = rowst[n+1];
  float ssum = 0.f, a8[8], S[10];
  #pragma unroll
  for(int j=0;j<8;j++) a8[j]=0.f;
  #pragma unroll
  for(int r=0;r<10;r++) S[r]=0.f;
  int i = lo + eg;
  if(i < hi){
    int s = esrc[i];
    const __hip_bfloat16* kr = kvb + (size_t)s*256;
    bf16x8 kc = *(const bf16x8*)&kr[c8];
    bf16x8 vc = *(const bf16x8*)&kr[128 + c8];
    const float* ef = efs + (size_t)i*12;
    float4 e0 = *(const float4*)&ef[0];
    float4 e1 = *(const float4*)&ef[4];
    float2 e2 = *(const float2*)&ef[8];
    while(true){
      int inext = i + 4;
      bool more = inext < hi;
      bf16x8 kn = kc, vn = vc;
      float4 f0 = e0, f1 = e1; float2 f2 = e2;
      if(more){
        int s2 = esrc[inext];
        const __hip_bfloat16* kr2 = kvb + (size_t)s2*256;
        kn = *(const bf16x8*)&kr2[c8];
        vn = *(const bf16x8*)&kr2[128 + c8];
        const float* ef2 = efs + (size_t)inext*12;
        f0 = *(const float4*)&ef2[0];
        f1 = *(const float4*)&ef2[4];
        f2 = *(const float2*)&ef2[8];
      }
      float d = 0.f;
      #pragma unroll
      for(int j=0;j<8;j++) d = fmaf(q8[j], b2f(kc[j]), d);
      d += __shfl_xor(d,1,64); d += __shfl_xor(d,2,64);   // per-head (quad) dot
      float lg = d;
      lg = fmaf(e0.x,QW[0],lg); lg = fmaf(e0.y,QW[1],lg);
      lg = fmaf(e0.z,QW[2],lg); lg = fmaf(e0.w,QW[3],lg);
      lg = fmaf(e1.x,QW[4],lg); lg = fmaf(e1.y,QW[5],lg);
      lg = fmaf(e1.z,QW[6],lg); lg = fmaf(e1.w,QW[7],lg);
      lg = fmaf(e2.x,QW[8],lg); lg = fmaf(e2.y,QW[9],lg);
      lg *= 0.17677669529663687f;
      lg = fminf(lg, 80.f);
      float w = __expf(lg);
      ssum += w;
      #pragma unroll
      for(int j=0;j<8;j++) a8[j] = fmaf(w, b2f(vc[j]), a8[j]);
      S[0]=fmaf(w,e0.x,S[0]); S[1]=fmaf(w,e0.y,S[1]); S[2]=fmaf(w,e0.z,S[2]);
      S[3]=fmaf(w,e0.w,S[3]); S[4]=fmaf(w,e1.x,S[4]); S[5]=fmaf(w,e1.y,S[5]);
      S[6]=fmaf(w,e1.z,S[6]); S[7]=fmaf(w,e1.w,S[7]); S[8]=fmaf(w,e2.x,S[8]);
      S[9]=fmaf(w,e2.y,S[9]);
      if(!more) break;
      kc = kn; vc = vn; e0 = f0; e1 = f1; e2 = f2;
      i = inext;
    }
  }
  // per-eg fold S -> o8 (linear in S, so fold before the reduce)
  float o8[8];
  #pragma unroll
  for(int j=0;j<8;j++) o8[j]=a8[j];
  #pragma unroll
  for(int r=0;r<10;r++){
    float s=S[r];
    float4 wa = *(const float4*)&WeL[r*128+c8];
    float4 wb = *(const float4*)&WeL[r*128+c8+4];
    o8[0]=fmaf(s,wa.x,o8[0]); o8[1]=fmaf(s,wa.y,o8[1]);
    o8[2]=fmaf(s,wa.z,o8[2]); o8[3]=fmaf(s,wa.w,o8[3]);
    o8[4]=fmaf(s,wb.x,o8[4]); o8[5]=fmaf(s,wb.y,o8[5]);
    o8[6]=fmaf(s,wb.z,o8[6]); o8[7]=fmaf(s,wb.w,o8[7]);
  }
  // cross-eg reduce: 9 values
  #pragma unroll
  for(int m=16;m<64;m<<=1){
    ssum += __shfl_xor(ssum,m,64);
    #pragma unroll
    for(int j=0;j<8;j++) o8[j] += __shfl_xor(o8[j],m,64);
  }
  float inv = (hi>lo)? 1.f/ssum : 0.f;
  #pragma unroll
  for(int j=0;j<8;j++) o8[j] *= inv;
  float xr8[8];
  {
    bf16x8 xv = *(const bf16x8*)&rowq[128 + c8];
    #pragma unroll
    for(int j=0;j<8;j++) xr8[j] = b2f(xv[j]);
  }
  float pb = 0.f;
  {
    float4 a0=*(const float4*)&Wb[c8],     a1=*(const float4*)&Wb[c8+4];
    float4 b0=*(const float4*)&Wb[128+c8], b1=*(const float4*)&Wb[128+c8+4];
    float4 c0=*(const float4*)&Wb[256+c8], c1=*(const float4*)&Wb[256+c8+4];
    float wb0[8]={a0.x,a0.y,a0.z,a0.w,a1.x,a1.y,a1.z,a1.w};
    float wb1[8]={b0.x,b0.y,b0.z,b0.w,b1.x,b1.y,b1.z,b1.w};
    float wb2[8]={c0.x,c0.y,c0.z,c0.w,c1.x,c1.y,c1.z,c1.w};
    #pragma unroll
    for(int j=0;j<8;j++)
      pb += o8[j]*wb0[j] + xr8[j]*wb1[j] + (o8[j]-xr8[j])*wb2[j];
  }
  pb = wsum16(pb);
  float beta = sigm_(pb);
  float h8[8], s1=0.f, s2=0.f;
  {
    bf16x8 hv = *(const bf16x8*)&hn[(size_t)n*128 + c8];
    #pragma unroll
    for(int j=0;j<8;j++){
      float u = beta*xr8[j] + (1.f-beta)*o8[j];
      float x = b2f(hv[j]) + sp_(u);
      h8[j]=x; s1+=x; s2+=x*x;
    }
  }
  s1 = wsum16(s1); s2 = wsum16(s2);
  float mu = s1*(1.f/128.f);
  float var = s2*(1.f/128.f) - mu*mu;
  float rsg = rsqrtf(var + 1e-5f);
  if(eg==0){
    float4 g0=*(const float4*)&lng[c8], g1=*(const float4*)&lng[c8+4];
    float4 bb0=*(const float4*)&lnb[c8], bb1=*(const float4*)&lnb[c8+4];
    float g8[8]={g0.x,g0.y,g0.z,g0.w,g1.x,g1.y,g1.z,g1.w};
    float lb8[8]={bb0.x,bb0.y,bb0.z,bb0.w,bb1.x,bb1.y,bb1.z,bb1.w};
    bf16x8 o;
    #pragma unroll
    for(int j=0;j<8;j++) o[j] = f2bs((h8[j]-mu)*rsg*g8[j] + lb8[j]);
    *(bf16x8*)&hn2[(size_t)n*128 + c8] = o;
  }
}

// ---------------- fused FFN: 3 chained GEMMs, fragment-flat W, LDS inter ----------------
__global__ __launch_bounds__(256) void ffn_fused(
    const __hip_bfloat16* __restrict__ hn2, const __hip_bfloat16* __restrict__ Wf,
    const float* __restrict__ b1, const float* __restrict__ b2,
    const float* __restrict__ b3, const float* __restrict__ lng,
    const float* __restrict__ lnb, float* __restrict__ hout,
    __hip_bfloat16* __restrict__ hnout, int N){
  __shared__ __hip_bfloat16 WsF[16384];
  __shared__ __hip_bfloat16 inter[2][64][IPAD];
  int row0 = blockIdx.x*64;
  int tid = threadIdx.x, lane = tid&63, wv = tid>>6;
  int ql = lane>>4, il = lane&15;

  auto stage = [&](const __hip_bfloat16* Wp){
    #pragma unroll
    for(int i=0;i<8;i++){
      int o = (tid + 256*i)*8;
      *(float4*)&WsF[o] = *(const float4*)&Wp[o];
    }
  };
  auto loadbias = [&](const float* bp, float* bl8){
    float4 x0 = *(const float4*)&bp[il*8];
    float4 x1 = *(const float4*)&bp[il*8+4];
    bl8[0]=x0.x; bl8[1]=x0.y; bl8[2]=x0.z; bl8[3]=x0.w;
    bl8[4]=x1.x; bl8[5]=x1.y; bl8[6]=x1.z; bl8[7]=x1.w;
  };

  f32x4 acc[8];
  bf16x8 af[4];
  // ---- FFN1 (A from global) ----
  stage(Wf);
  {
    int r = row0 + wv*16 + il;
    r = (r<N)? r : (N-1);
    const __hip_bfloat16* ap = hn2 + (size_t)r*128 + ql*8;
    #pragma unroll
    for(int kc=0;kc<4;kc++) af[kc] = *(const bf16x8*)(ap + kc*32);
  }
  __syncthreads();
  #pragma unroll
  for(int nj=0;nj<8;nj++) acc[nj] = (f32x4){0.f,0.f,0.f,0.f};
  #pragma unroll
  for(int kc=0;kc<4;kc++)
    #pragma unroll
    for(int nj=0;nj<8;nj++){
      bf16x8 bb = *(bf16x8*)&WsF[((kc*8+nj)*64 + lane)*8];
      acc[nj] = __builtin_amdgcn_mfma_f32_16x16x32_bf16(af[kc], bb, acc[nj], 0,0,0);
    }
  {
    float bl8[8]; loadbias(b1, bl8);
    #pragma unroll
    for(int r=0;r<4;r++){
      int lr = wv*16 + ql*4 + r;
      bf16x8 o;
      #pragma unroll
      for(int nj=0;nj<8;nj++) o[nj] = f2bs(sp_(acc[nj][r] + bl8[nj]));
      *(bf16x8*)&inter[0][lr][il*8] = o;
    }
  }
  __syncthreads();
  // ---- FFN2 (A from inter[0]) ----
  stage(Wf + 16384);
  #pragma unroll
  for(int kc=0;kc<4;kc++) af[kc] = *(bf16x8*)&inter[0][wv*16+il][ql*8 + kc*32];
  __syncthreads();
  #pragma unroll
  for(int nj=0;nj<8;nj++) acc[nj] = (f32x4){0.f,0.f,0.f,0.f};
  #pragma unroll
  for(int kc=0;kc<4;kc++)
    #pragma unroll
    for(int nj=0;nj<8;nj++){
      bf16x8 bb = *(bf16x8*)&WsF[((kc*8+nj)*64 + lane)*8];
      acc[nj] = __builtin_amdgcn_mfma_f32_16x16x32_bf16(af[kc], bb, acc[nj], 0,0,0);
    }
  {
    float bl8[8]; loadbias(b2, bl8);
    #pragma unroll
    for(int r=0;r<4;r++){
      int lr = wv*16 + ql*4 + r;
      bf16x8 o;
      #pragma unroll
      for(int nj=0;nj<8;nj++) o[nj] = f2bs(sp_(acc[nj][r] + bl8[nj]));
      *(bf16x8*)&inter[1][lr][il*8] = o;
    }
  }
  __syncthreads();
  // ---- FFN3 (A from inter[1]) + epilogue ----
  stage(Wf + 2*16384);
  #pragma unroll
  for(int kc=0;kc<4;kc++) af[kc] = *(bf16x8*)&inter[1][wv*16+il][ql*8 + kc*32];
  __syncthreads();
  #pragma unroll
  for(int nj=0;nj<8;nj++) acc[nj] = (f32x4){0.f,0.f,0.f,0.f};
  #pragma unroll
  for(int kc=0;kc<4;kc++)
    #pragma unroll
    for(int nj=0;nj<8;nj++){
      bf16x8 bb = *(bf16x8*)&WsF[((kc*8+nj)*64 + lane)*8];
      acc[nj] = __builtin_amdgcn_mfma_f32_16x16x32_bf16(af[kc], bb, acc[nj], 0,0,0);
    }
  {
    float bl8[8]; loadbias(b3, bl8);
    float lg8[8], lb8[8];
    loadbias(lng, lg8); loadbias(lnb, lb8);
    #pragma unroll
    for(int r=0;r<4;r++){
      int rr = row0 + wv*16 + ql*4 + r;
      if(rr >= N) continue;     // uniform across il -> shfl-safe
      bf16x8 rv = *(const bf16x8*)&hn2[(size_t)rr*128 + il*8];
      float t8[8], s1=0.f, s2=0.f;
      #pragma unroll
      for(int nj=0;nj<8;nj++){
        float x = sp_(acc[nj][r] + bl8[nj]) + b2f(rv[nj]);
        t8[nj]=x; s1+=x; s2+=x*x;
      }
      s1 = wsum16(s1); s2 = wsum16(s2);
      float mu = s1*(1.f/128.f);
      float var = s2*(1.f/128.f) - mu*mu;
      float rsg = rsqrtf(var + 1e-5f);
      *(float4*)&hout[(size_t)rr*128 + il*8]     = make_float4(t8[0],t8[1],t8[2],t8[3]);
      *(float4*)&hout[(size_t)rr*128 + il*8 + 4] = make_float4(t8[4],t8[5],t8[6],t8[7]);
      bf16x8 o;
      #pragma unroll
      for(int nj=0;nj<8;nj++) o[nj] = f2bs((t8[nj]-mu)*rsg*lg8[nj] + lb8[nj]);
      *(bf16x8*)&hnout[(size_t)rr*128 + il*8] = o;
    }
  }
}

// ---------------- pooling + output head (block per graph) ----------------
__global__ void pool_head(const float* __restrict__ h, const int* __restrict__ batch,
                          const float* __restrict__ Wo1, const float* __restrict__ bo1,
                          const float* __restrict__ Wo2, const float* __restrict__ bo2,
                          float* __restrict__ out, int N){
  int gid = blockIdx.x;
  int t = threadIdx.x;  // 128 threads
  int lo = lb_(batch, N, gid), hi = lb_(batch, N, gid+1);
  __shared__ float pl[128];
  __shared__ float red[128];
  float s = 0.f;
  for(int i=lo;i<hi;i++) s += h[(size_t)i*HID + t];
  pl[t] = s;
  __syncthreads();
  float acc = bo1[t];
  for(int c=0;c<128;c++) acc = fmaf(pl[c], Wo1[c*HID+t], acc);
  red[t] = sp_(acc)*Wo2[t];
  __syncthreads();
  for(int off=64;off>0;off>>=1){
    if(t<off) red[t]+=red[t+off];
    __syncthreads();
  }
  if(t==0) out[gid] = red[0] + bo2[0];
}

extern "C" void kernel_launch(void* const* d_in, const int* in_sizes, int n_in,
                              void* d_out, int out_size, void* d_ws, size_t ws_size,
                              hipStream_t stream){
  const float* h_in = (const float*)d_in[0];
  const float* pos  = (const float*)d_in[1];
  const float* ew   = (const float*)d_in[2];
  const float* Wq = (const float*)d_in[3];  const float* bq = (const float*)d_in[4];
  const float* Wk = (const float*)d_in[5];  const float* bk = (const float*)d_in[6];
  const float* Wv = (const float*)d_in[7];  const float* bv = (const float*)d_in[8];
  const float* We = (const float*)d_in[9];
  const float* Wsk= (const float*)d_in[10]; const float* bsk=(const float*)d_in[11];
  const float* Wbeta=(const float*)d_in[12];
  const float* W1=(const float*)d_in[13]; const float* b1=(const float*)d_in[14];
  const float* W2=(const float*)d_in[15]; const float* b2=(const float*)d_in[16];
  const float* W3=(const float*)d_in[17]; const float* b3=(const float*)d_in[18];
  const float* lng=(const float*)d_in[19]; const float* lnb=(const float*)d_in[20];
  const float* Wo1=(const float*)d_in[21]; const float* bo1=(const float*)d_in[22];
  const float* Wo2=(const float*)d_in[23]; const float* bo2=(const float*)d_in[24];
  const int* ei    = (const int*)d_in[25];
  const int* batch = (const int*)d_in[26];
  int N = in_sizes[0]/HID;
  int E = in_sizes[2];
  int G = out_size;
  float* out = (float*)d_out;

  char* ws = (char*)d_ws;
  size_t off=0;
  auto alloc=[&](size_t bytes)->char*{
    char* p = ws + off;
    off = (off + bytes + 255) & ~(size_t)255;
    return p;
  };
  float* efs   =(float*)alloc((size_t)E*12*4);
  int* esrc    =(int*)  alloc((size_t)E*4);
  int* csr     =(int*)  alloc((size_t)E*4);
  int* counts  =(int*)  alloc((size_t)N*4);
  int* counts2 =(int*)  alloc((size_t)N*4);
  int* rowst   =(int*)  alloc((size_t)(N+1)*4);
  int* tmp     =(int*)  alloc((size_t)N*4);
  int* bsums   =(int*)  alloc(256*4);
  int* boffs   =(int*)  alloc(256*4);
  __hip_bfloat16* hn   =(__hip_bfloat16*)alloc((size_t)N*HID*2);
  __hip_bfloat16* hn2  =(__hip_bfloat16*)alloc((size_t)N*HID*2);
  __hip_bfloat16* qsb  =(__hip_bfloat16*)alloc((size_t)N*256*2);
  __hip_bfloat16* kvb  =(__hip_bfloat16*)alloc((size_t)N*256*2);
  float* qwb   =(float*)alloc((size_t)N*48*4);
  float* hcur  =(float*)alloc((size_t)N*HID*4);
  __hip_bfloat16* Wqkvs_t =(__hip_bfloat16*)alloc((size_t)NLAYER*5*16384*2);
  __hip_bfloat16* Wffn_t  =(__hip_bfloat16*)alloc((size_t)NLAYER*3*16384*2);
  float* bqkvs =(float*)alloc((size_t)NLAYER*640*4);

  int ebl = (E+255)/256;
  int nb  = (N+255)/256;
  int nwb = (N+3)/4;
  int nrb128 = (N+127)/128;
  int nrb64  = (N+63)/64;
  dim3 gqkvs(5, nrb128);

  hipMemsetAsync(counts, 0, (size_t)N*4, stream);
  hipMemsetAsync(counts2,0, (size_t)N*4, stream);
  count_dst<<<ebl,256,0,stream>>>(ei,counts,E);
  scan1<<<nb,256,0,stream>>>(counts,tmp,bsums,N);
  scan2<<<1,256,0,stream>>>(bsums,boffs,nb);
  finalize_rs<<<nb,256,0,stream>>>(tmp,boffs,rowst,N);
  csr_scatter<<<ebl,256,0,stream>>>(ei,rowst,counts2,csr,E);
  sort_seg<<<nb,256,0,stream>>>(rowst,csr,N);          // deterministic order
  edge_feat<<<ebl,256,0,stream>>>(pos,ew,ei,csr,efs,esrc,E);
  {
    int tot = NLAYER*5*16384 + NLAYER*3*16384 + NLAYER*640;
    pack_w<<<(tot+255)/256,256,0,stream>>>(Wq,Wk,Wv,Wsk,bq,bk,bv,bsk,We,W1,W2,W3,
                                           Wqkvs_t,bqkvs,Wffn_t);
  }

  ln_node<<<nwb,256,0,stream>>>(h_in,lng,lnb,hn,N);
  for(int l=0;l<NLAYER;l++){
    const float* We_l = We + (size_t)l*(KRBF+1)*HID;
    const float* Wb_l = Wbeta + (size_t)l*3*HID;
    const float* b1_l = b1 + (size_t)l*HID;
    const float* b2_l = b2 + (size_t)l*HID;
    const float* b3_l = b3 + (size_t)l*HID;

    gemm_qkvs<<<gqkvs,256,0,stream>>>(hn, Wqkvs_t + (size_t)l*5*16384,
                                      bqkvs + l*640, qsb, kvb, qwb, N);
    attn_fused4<<<nwb,256,0,stream>>>(qsb,kvb,qwb,efs,esrc,We_l,rowst,hn,
                                      Wb_l,lng,lnb,hn2,N);
    ffn_fused<<<nrb64,256,0,stream>>>(hn2, Wffn_t + (size_t)l*3*16384,
                                      b1_l,b2_l,b3_l,lng,lnb,hcur,hn,N);
  }
  pool_head<<<G,128,0,stream>>>(hcur,batch,Wo1,bo1,Wo2,bo2,out,N);
}

// Round 12
// 883.062 us; speedup vs baseline: 1.7883x; 1.0494x over previous
//
#include <hip/hip_runtime.h>
#include <hip/hip_bf16.h>
#include <math.h>

#define HID 128
#define KRBF 9
#define NLAYER 3
#define IPAD 136    // inter LDS row stride (halfwords): 272B -> all rows 16B-aligned

typedef __attribute__((ext_vector_type(8))) short bf16x8;
typedef __attribute__((ext_vector_type(4))) float f32x4;

__device__ __forceinline__ float sp_(float x){ return fmaxf(x,0.f) + log1pf(expf(-fabsf(x))); }
__device__ __forceinline__ float sigm_(float x){ return 1.f/(1.f+expf(-x)); }
__device__ __forceinline__ float b2f(short s){
  union{unsigned u; float f;} x; x.u = ((unsigned)(unsigned short)s)<<16; return x.f;
}
__device__ __forceinline__ short f2bs(float x){
  __hip_bfloat16 b = __float2bfloat16(x);
  return *reinterpret_cast<short*>(&b);
}
__device__ __forceinline__ float wsum64(float v){
  #pragma unroll
  for(int m=1;m<64;m<<=1) v += __shfl_xor(v,m,64);
  return v;
}
__device__ __forceinline__ float wsum16(float v){
  #pragma unroll
  for(int m=1;m<16;m<<=1) v += __shfl_xor(v,m,64);
  return v;
}
__device__ __forceinline__ float2 ldbf2(const __hip_bfloat16* p){
  __hip_bfloat162 b = *(const __hip_bfloat162*)p;
  return make_float2(__bfloat162float(b.x), __bfloat162float(b.y));
}
__device__ __forceinline__ int lb_(const int* __restrict__ a, int n, int key){
  int lo=0, hi=n;
  while(lo<hi){ int mid=(lo+hi)>>1; if(a[mid]<key) lo=mid+1; else hi=mid; }
  return lo;
}

// ---------------- CSR ----------------
__global__ void count_dst(const int* __restrict__ ei, int* __restrict__ counts, int E){
  int e = blockIdx.x*256+threadIdx.x;
  if(e<E) atomicAdd(&counts[ei[E+e]],1);
}
__global__ void scan1(const int* __restrict__ counts, int* __restrict__ tmp,
                      int* __restrict__ bsums, int N){
  __shared__ int lds[256];
  int t = threadIdx.x; int idx = blockIdx.x*256+t;
  int v = (idx<N)? counts[idx]:0;
  lds[t]=v; __syncthreads();
  for(int off=1;off<256;off<<=1){
    int x = (t>=off)? lds[t-off]:0;
    __syncthreads();
    lds[t]+=x; __syncthreads();
  }
  if(idx<N) tmp[idx]=lds[t];
  if(t==255) bsums[blockIdx.x]=lds[255];
}
__global__ void scan2(const int* __restrict__ bsums, int* __restrict__ boffs, int nb){
  __shared__ int lds[256];
  int t=threadIdx.x;
  int v = (t<nb)? bsums[t]:0;
  lds[t]=v; __syncthreads();
  for(int off=1;off<256;off<<=1){
    int x=(t>=off)?lds[t-off]:0;
    __syncthreads();
    lds[t]+=x; __syncthreads();
  }
  if(t<nb) boffs[t] = lds[t]-v; // exclusive
}
__global__ void finalize_rs(const int* __restrict__ tmp, const int* __restrict__ boffs,
                            int* __restrict__ row_start, int N){
  int idx = blockIdx.x*256+threadIdx.x;
  if(idx<N) row_start[idx+1] = tmp[idx] + boffs[idx>>8];
  if(idx==0) row_start[0]=0;
}
__global__ void csr_scatter(const int* __restrict__ ei, const int* __restrict__ rowst,
                            int* __restrict__ counts2, int* __restrict__ csr, int E){
  int e = blockIdx.x*256+threadIdx.x;
  if(e>=E) return;
  int d = ei[E+e];
  int p = rowst[d] + atomicAdd(&counts2[d],1);
  csr[p] = e;
}
// deterministic segment order: insertion-sort each node's edge ids ascending
__global__ void sort_seg(const int* __restrict__ rowst, int* __restrict__ csr, int N){
  int n = blockIdx.x*256+threadIdx.x;
  if(n>=N) return;
  int lo=rowst[n], hi=rowst[n+1];
  for(int i=lo+1;i<hi;i++){
    int v=csr[i]; int j=i-1;
    while(j>=lo && csr[j]>v){ csr[j+1]=csr[j]; j--; }
    csr[j+1]=v;
  }
}
__global__ void edge_feat(const float* __restrict__ pos, const float* __restrict__ ew,
                          const int* __restrict__ ei, const int* __restrict__ csr,
                          float* __restrict__ efs, int* __restrict__ esrc, int E){
  int p = blockIdx.x*256 + threadIdx.x;
  if(p>=E) return;
  int e = csr[p];
  int s = ei[e], d = ei[E+e];
  float dx = pos[d*3+0]-pos[s*3+0];
  float dy = pos[d*3+1]-pos[s*3+1];
  float dz = pos[d*3+2]-pos[s*3+2];
  float D = sqrtf(dx*dx+dy*dy+dz*dz);
  float x = D*0.1f;
  float cut = 0.f;
  if(x < 1.f){ float x3=x*x*x, x4=x3*x, x5=x4*x; cut = 1.f - 6.f*x5 + 15.f*x4 - 10.f*x3; }
  float ed = expf(-D);
  const double e10 = 4.5399929762484854e-05; // exp(-10)
  const float step  = (float)((e10 - 1.0)/8.0);
  const float width = (float)((4.5/(1.0-e10))*(4.5/(1.0-e10)));
  float r12[12];
  #pragma unroll
  for(int k=0;k<KRBF;k++){
    float c = 1.0f + k*step;
    float dd = ed - c;
    r12[k] = cut*expf(-width*dd*dd);
  }
  r12[9] = ew[e]; r12[10]=0.f; r12[11]=0.f;
  float* o = efs + (size_t)p*12;
  *(float4*)&o[0] = *(float4*)&r12[0];
  *(float4*)&o[4] = *(float4*)&r12[4];
  *(float4*)&o[8] = *(float4*)&r12[8];
  esrc[p] = s;
}

// ---------------- weight packing: MFMA fragment-flat order ----------------
__global__ void pack_w(const float* __restrict__ Wq, const float* __restrict__ Wk,
                       const float* __restrict__ Wv, const float* __restrict__ Wsk,
                       const float* __restrict__ bq, const float* __restrict__ bk,
                       const float* __restrict__ bv, const float* __restrict__ bsk,
                       const float* __restrict__ We,
                       const float* __restrict__ W1, const float* __restrict__ W2,
                       const float* __restrict__ W3,
                       __hip_bfloat16* __restrict__ Wqkvs, float* __restrict__ bqkvs,
                       __hip_bfloat16* __restrict__ Wffn){
  int idx = blockIdx.x*256 + threadIdx.x;
  const int QT = NLAYER*5*16384;
  const int FT = NLAYER*3*16384;
  const int BT = NLAYER*640;
  if(idx < QT){
    int l = idx / (5*16384);
    int rem = idx - l*(5*16384);
    int cb = rem >> 14;
    int t = rem & 16383;
    int j = t&7; int lane = (t>>3)&63; int blk = t>>9;
    int kc = blk>>3, nj = blk&7, ql = lane>>4, il = lane&15;
    int k = kc*32 + ql*8 + j;
    int gcol = cb*128 + il*8 + nj;
    float v = 0.f;
    if(gcol < 512){
      const float* src = (gcol<128)?Wq:((gcol<256)?Wk:((gcol<384)?Wv:Wsk));
      v = src[(size_t)l*16384 + k*128 + (gcol&127)];
    } else if(gcol < 552){
      int jj = gcol-512; int h=jj/10; int r=jj-10*h;
      const float* wq = Wq + (size_t)l*16384 + k*128;
      const float* we = We + (size_t)l*1280 + r*128;
      float acc=0.f;
      #pragma unroll 8
      for(int c=32*h;c<32*h+32;c++) acc = fmaf(wq[c], we[c], acc);
      v = acc;
    }
    Wqkvs[idx] = __float2bfloat16(v);
  } else if(idx < QT+FT){
    int r0 = idx - QT;
    int l = r0 / (3*16384);
    int rem = r0 - l*(3*16384);
    int f = rem >> 14;
    int t = rem & 16383;
    int j = t&7; int lane = (t>>3)&63; int blk = t>>9;
    int kc = blk>>3, nj = blk&7, ql = lane>>4, il = lane&15;
    int k = kc*32 + ql*8 + j;
    int gcol = il*8 + nj;
    const float* src = (f==0)?W1:((f==1)?W2:W3);
    Wffn[r0] = __float2bfloat16(src[(size_t)l*16384 + k*128 + gcol]);
  } else if(idx < QT+FT+BT){
    int j = idx - QT - FT;
    int l = j/640; int col = j - l*640;   // bias in NATURAL col order
    float v = 0.f;
    if(col<512){
      const float* src = (col<128)?bq:((col<256)?bk:((col<384)?bv:bsk));
      v = src[l*128 + (col&127)];
    } else if(col<552){
      int jj=col-512; int h=jj/10; int r=jj-10*h;
      const float* bqp = bq + l*128;
      const float* we = We + (size_t)l*1280 + r*128;
      float acc=0.f;
      for(int c=32*h;c<32*h+32;c++) acc = fmaf(bqp[c], we[c], acc);
      v = acc;
    }
    bqkvs[j] = v;
  }
}

// ---------------- LayerNorm (wave per node) fp32 -> bf16 (layer 0 only) ----------------
__global__ void ln_node(const float* __restrict__ h, const float* __restrict__ g,
                        const float* __restrict__ b, __hip_bfloat16* __restrict__ hn, int N){
  int n = blockIdx.x*4 + (threadIdx.x>>6);
  if(n>=N) return;
  int lane = threadIdx.x & 63;
  int c = 2*lane;
  float2 v = *(const float2*)&h[(size_t)n*HID + c];
  float s1 = wsum64(v.x+v.y);
  float s2 = wsum64(v.x*v.x+v.y*v.y);
  float mu = s1*(1.f/HID);
  float var = s2*(1.f/HID) - mu*mu;
  float rs = rsqrtf(var + 1e-5f);
  __hip_bfloat162 o;
  o.x = __float2bfloat16((v.x-mu)*rs*g[c]   + b[c]);
  o.y = __float2bfloat16((v.y-mu)*rs*g[c+1] + b[c+1]);
  *(__hip_bfloat162*)&hn[(size_t)n*HID + c] = o;
}

// ---------------- qkvs GEMM: 128 rows x 5 col-blocks, fragment-flat LDS ----------------
__global__ __launch_bounds__(256) void gemm_qkvs(
    const __hip_bfloat16* __restrict__ A, const __hip_bfloat16* __restrict__ Wt,
    const float* __restrict__ bias,
    __hip_bfloat16* __restrict__ qsO, __hip_bfloat16* __restrict__ kvO,
    float* __restrict__ qwO, int N){
  __shared__ __hip_bfloat16 WsF[16384];
  int row0 = blockIdx.y*128;
  int cb = blockIdx.x;
  int tid = threadIdx.x;
  {
    const __hip_bfloat16* Wp = Wt + (size_t)cb*16384;
    #pragma unroll
    for(int i=0;i<8;i++){
      int o = (tid + 256*i)*8;
      *(float4*)&WsF[o] = *(const float4*)&Wp[o];
    }
  }
  int lane = tid&63;
  int m0 = (tid>>6)*32;
  int ql = lane>>4, il = lane&15;
  bf16x8 af[2][4];
  #pragma unroll
  for(int mi=0;mi<2;mi++){
    int r = row0 + m0 + mi*16 + il;
    r = (r < N) ? r : (N-1);
    const __hip_bfloat16* ap = A + (size_t)r*128 + ql*8;
    #pragma unroll
    for(int kc=0;kc<4;kc++) af[mi][kc] = *(const bf16x8*)(ap + kc*32);
  }
  __syncthreads();
  f32x4 acc[2][8];
  #pragma unroll
  for(int mi=0;mi<2;mi++)
    #pragma unroll
    for(int nj=0;nj<8;nj++) acc[mi][nj] = (f32x4){0.f,0.f,0.f,0.f};
  #pragma unroll
  for(int kc=0;kc<4;kc++){
    #pragma unroll
    for(int nj=0;nj<8;nj++){
      bf16x8 bb = *(bf16x8*)&WsF[((kc*8+nj)*64 + lane)*8];
      #pragma unroll
      for(int mi=0;mi<2;mi++)
        acc[mi][nj] = __builtin_amdgcn_mfma_f32_16x16x32_bf16(af[mi][kc], bb, acc[mi][nj], 0,0,0);
    }
  }
  float bl8[8];
  {
    float4 b0 = *(const float4*)&bias[cb*128 + il*8];
    float4 b1 = *(const float4*)&bias[cb*128 + il*8 + 4];
    bl8[0]=b0.x; bl8[1]=b0.y; bl8[2]=b0.z; bl8[3]=b0.w;
    bl8[4]=b1.x; bl8[5]=b1.y; bl8[6]=b1.z; bl8[7]=b1.w;
  }
  #pragma unroll
  for(int mi=0;mi<2;mi++){
    #pragma unroll
    for(int r=0;r<4;r++){
      int rr = row0 + m0 + mi*16 + ql*4 + r;
      if(rr >= N) continue;
      if(cb < 4){
        bf16x8 o;
        #pragma unroll
        for(int nj=0;nj<8;nj++) o[nj] = f2bs(acc[mi][nj][r] + bl8[nj]);
        __hip_bfloat16* dst;
        if(cb==0)      dst = qsO + (size_t)rr*256 + il*8;          // q
        else if(cb==1) dst = kvO + (size_t)rr*256 + il*8;          // k
        else if(cb==2) dst = kvO + (size_t)rr*256 + 128 + il*8;    // v
        else           dst = qsO + (size_t)rr*256 + 128 + il*8;    // skip
        *(bf16x8*)dst = o;
      } else if(il < 5){
        #pragma unroll
        for(int nj=0;nj<8;nj++){
          int g = il*8 + nj;            // < 40
          int h = g/10, rb = g - 10*h;
          qwO[(size_t)rr*48 + h*12 + rb] = acc[mi][nj][r] + bl8[nj];
        }
      }
    }
  }
}

// ---------------- attention core: logits + softmax (no-max) + aggregation ----------------
__global__ __launch_bounds__(256) void attn_fused6(
    const __hip_bfloat16* __restrict__ qs, const __hip_bfloat16* __restrict__ kvb,
    const float* __restrict__ qwb, const float* __restrict__ efs,
    const int* __restrict__ esrc, const float* __restrict__ WeL,
    const int* __restrict__ rowst, float* __restrict__ att, int N){
  int n = blockIdx.x*4 + (threadIdx.x>>6);
  if(n>=N) return;
  int lane = threadIdx.x & 63;
  int eg = lane>>4, sl = lane&15;
  int c8 = sl*8, hd = sl>>2;
  const __hip_bfloat16* rowq = qs + (size_t)n*256;
  float q8[8];
  {
    bf16x8 qv = *(const bf16x8*)&rowq[c8];
    #pragma unroll
    for(int j=0;j<8;j++) q8[j] = b2f(qv[j]);
  }
  const float* qwp = qwb + (size_t)n*48 + hd*12;
  float4 qa = *(const float4*)qwp;
  float4 qb = *(const float4*)(qwp+4);
  float2 qc = *(const float2*)(qwp+8);
  float QW[10] = {qa.x,qa.y,qa.z,qa.w,qb.x,qb.y,qb.z,qb.w,qc.x,qc.y};
  int lo = rowst[n], hi = rowst[n+1];
  float ssum = 0.f, a8[8], S[10];
  #pragma unroll
  for(int j=0;j<8;j++) a8[j]=0.f;
  #pragma unroll
  for(int r=0;r<10;r++) S[r]=0.f;
  for(int i=lo+eg; i<hi; i+=4){
    int s = esrc[i];
    const __hip_bfloat16* kr = kvb + (size_t)s*256;
    bf16x8 kc = *(const bf16x8*)&kr[c8];
    bf16x8 vc = *(const bf16x8*)&kr[128 + c8];
    const float* ef = efs + (size_t)i*12;
    float4 e0 = *(const float4*)&ef[0];
    float4 e1 = *(const float4*)&ef[4];
    float2 e2 = *(const float2*)&ef[8];
    float d = 0.f;
    #pragma unroll
    for(int j=0;j<8;j++) d = fmaf(q8[j], b2f(kc[j]), d);
    d += __shfl_xor(d,1,64); d += __shfl_xor(d,2,64);   // per-head (quad) dot
    float lg = d;
    lg = fmaf(e0.x,QW[0],lg); lg = fmaf(e0.y,QW[1],lg);
    lg = fmaf(e0.z,QW[2],lg); lg = fmaf(e0.w,QW[3],lg);
    lg = fmaf(e1.x,QW[4],lg); lg = fmaf(e1.y,QW[5],lg);
    lg = fmaf(e1.z,QW[6],lg); lg = fmaf(e1.w,QW[7],lg);
    lg = fmaf(e2.x,QW[8],lg); lg = fmaf(e2.y,QW[9],lg);
    lg *= 0.17677669529663687f;
    lg = fminf(lg, 80.f);
    float w = __expf(lg);
    ssum += w;
    #pragma unroll
    for(int j=0;j<8;j++) a8[j] = fmaf(w, b2f(vc[j]), a8[j]);
    S[0]=fmaf(w,e0.x,S[0]); S[1]=fmaf(w,e0.y,S[1]); S[2]=fmaf(w,e0.z,S[2]);
    S[3]=fmaf(w,e0.w,S[3]); S[4]=fmaf(w,e1.x,S[4]); S[5]=fmaf(w,e1.y,S[5]);
    S[6]=fmaf(w,e1.z,S[6]); S[7]=fmaf(w,e1.w,S[7]); S[8]=fmaf(w,e2.x,S[8]);
    S[9]=fmaf(w,e2.y,S[9]);
  }
  float o8[8];
  #pragma unroll
  for(int j=0;j<8;j++) o8[j]=a8[j];
  #pragma unroll
  for(int r=0;r<10;r++){
    float s=S[r];
    float4 wa = *(const float4*)&WeL[r*128+c8];
    float4 wb = *(const float4*)&WeL[r*128+c8+4];
    o8[0]=fmaf(s,wa.x,o8[0]); o8[1]=fmaf(s,wa.y,o8[1]);
    o8[2]=fmaf(s,wa.z,o8[2]); o8[3]=fmaf(s,wa.w,o8[3]);
    o8[4]=fmaf(s,wb.x,o8[4]); o8[5]=fmaf(s,wb.y,o8[5]);
    o8[6]=fmaf(s,wb.z,o8[6]); o8[7]=fmaf(s,wb.w,o8[7]);
  }
  #pragma unroll
  for(int m=16;m<64;m<<=1){
    ssum += __shfl_xor(ssum,m,64);
    #pragma unroll
    for(int j=0;j<8;j++) o8[j] += __shfl_xor(o8[j],m,64);
  }
  if(eg==0){
    float inv = (hi>lo)? 1.f/ssum : 0.f;
    float4 v0 = make_float4(o8[0]*inv, o8[1]*inv, o8[2]*inv, o8[3]*inv);
    float4 v1 = make_float4(o8[4]*inv, o8[5]*inv, o8[6]*inv, o8[7]*inv);
    *(float4*)&att[(size_t)n*128 + c8]     = v0;
    *(float4*)&att[(size_t)n*128 + c8 + 4] = v1;
  }
}

// ---------------- beta-gate + residual + softplus + LN (wave per node, 2 ch/lane) ----------------
__global__ void combine_ln(const float* __restrict__ att, const __hip_bfloat16* __restrict__ qs,
                           const __hip_bfloat16* __restrict__ hn, const float* __restrict__ Wb,
                           const float* __restrict__ g, const float* __restrict__ b,
                           __hip_bfloat16* __restrict__ hn2, int N){
  int n = blockIdx.x*4 + (threadIdx.x>>6);
  if(n>=N) return;
  int lane = threadIdx.x&63;
  int c = 2*lane;
  float2 o  = *(const float2*)&att[(size_t)n*HID+c];
  float2 xr = ldbf2(&qs[(size_t)n*256 + 128 + c]);
  float bl = o.x*Wb[c] + o.y*Wb[c+1]
           + xr.x*Wb[HID+c] + xr.y*Wb[HID+c+1]
           + (o.x-xr.x)*Wb[2*HID+c] + (o.y-xr.y)*Wb[2*HID+c+1];
  bl = wsum64(bl);
  float beta = sigm_(bl);
  float u0 = beta*xr.x + (1.f-beta)*o.x;
  float u1 = beta*xr.y + (1.f-beta)*o.y;
  float2 hnv = ldbf2(&hn[(size_t)n*HID+c]);
  float h0 = hnv.x + sp_(u0);
  float h1 = hnv.y + sp_(u1);
  float s1 = wsum64(h0+h1);
  float s2 = wsum64(h0*h0+h1*h1);
  float mu = s1*(1.f/HID);
  float var = s2*(1.f/HID)-mu*mu;
  float rs = rsqrtf(var+1e-5f);
  __hip_bfloat162 outv;
  outv.x = __float2bfloat16((h0-mu)*rs*g[c]+b[c]);
  outv.y = __float2bfloat16((h1-mu)*rs*g[c+1]+b[c+1]);
  *(__hip_bfloat162*)&hn2[(size_t)n*HID+c] = outv;
}

// ---------------- fused FFN: 3 chained GEMMs, fragment-flat W, LDS inter ----------------
__global__ __launch_bounds__(256) void ffn_fused(
    const __hip_bfloat16* __restrict__ hn2, const __hip_bfloat16* __restrict__ Wf,
    const float* __restrict__ b1, const float* __restrict__ b2,
    const float* __restrict__ b3, const float* __restrict__ lng,
    const float* __restrict__ lnb, float* __restrict__ hout,
    __hip_bfloat16* __restrict__ hnout, int N){
  __shared__ __hip_bfloat16 WsF[16384];
  __shared__ __hip_bfloat16 inter[2][64][IPAD];
  int row0 = blockIdx.x*64;
  int tid = threadIdx.x, lane = tid&63, wv = tid>>6;
  int ql = lane>>4, il = lane&15;

  auto stage = [&](const __hip_bfloat16* Wp){
    #pragma unroll
    for(int i=0;i<8;i++){
      int o = (tid + 256*i)*8;
      *(float4*)&WsF[o] = *(const float4*)&Wp[o];
    }
  };
  auto loadbias = [&](const float* bp, float* bl8){
    float4 x0 = *(const float4*)&bp[il*8];
    float4 x1 = *(const float4*)&bp[il*8+4];
    bl8[0]=x0.x; bl8[1]=x0.y; bl8[2]=x0.z; bl8[3]=x0.w;
    bl8[4]=x1.x; bl8[5]=x1.y; bl8[6]=x1.z; bl8[7]=x1.w;
  };

  f32x4 acc[8];
  bf16x8 af[4];
  // ---- FFN1 (A from global) ----
  stage(Wf);
  {
    int r = row0 + wv*16 + il;
    r = (r<N)? r : (N-1);
    const __hip_bfloat16* ap = hn2 + (size_t)r*128 + ql*8;
    #pragma unroll
    for(int kc=0;kc<4;kc++) af[kc] = *(const bf16x8*)(ap + kc*32);
  }
  __syncthreads();
  #pragma unroll
  for(int nj=0;nj<8;nj++) acc[nj] = (f32x4){0.f,0.f,0.f,0.f};
  #pragma unroll
  for(int kc=0;kc<4;kc++)
    #pragma unroll
    for(int nj=0;nj<8;nj++){
      bf16x8 bb = *(bf16x8*)&WsF[((kc*8+nj)*64 + lane)*8];
      acc[nj] = __builtin_amdgcn_mfma_f32_16x16x32_bf16(af[kc], bb, acc[nj], 0,0,0);
    }
  {
    float bl8[8]; loadbias(b1, bl8);
    #pragma unroll
    for(int r=0;r<4;r++){
      int lr = wv*16 + ql*4 + r;
      bf16x8 o;
      #pragma unroll
      for(int nj=0;nj<8;nj++) o[nj] = f2bs(sp_(acc[nj][r] + bl8[nj]));
      *(bf16x8*)&inter[0][lr][il*8] = o;
    }
  }
  __syncthreads();
  // ---- FFN2 (A from inter[0]) ----
  stage(Wf + 16384);
  #pragma unroll
  for(int kc=0;kc<4;kc++) af[kc] = *(bf16x8*)&inter[0][wv*16+il][ql*8 + kc*32];
  __syncthreads();
  #pragma unroll
  for(int nj=0;nj<8;nj++) acc[nj] = (f32x4){0.f,0.f,0.f,0.f};
  #pragma unroll
  for(int kc=0;kc<4;kc++)
    #pragma unroll
    for(int nj=0;nj<8;nj++){
      bf16x8 bb = *(bf16x8*)&WsF[((kc*8+nj)*64 + lane)*8];
      acc[nj] = __builtin_amdgcn_mfma_f32_16x16x32_bf16(af[kc], bb, acc[nj], 0,0,0);
    }
  {
    float bl8[8]; loadbias(b2, bl8);
    #pragma unroll
    for(int r=0;r<4;r++){
      int lr = wv*16 + ql*4 + r;
      bf16x8 o;
      #pragma unroll
      for(int nj=0;nj<8;nj++) o[nj] = f2bs(sp_(acc[nj][r] + bl8[nj]));
      *(bf16x8*)&inter[1][lr][il*8] = o;
    }
  }
  __syncthreads();
  // ---- FFN3 (A from inter[1]) + epilogue ----
  stage(Wf + 2*16384);
  #pragma unroll
  for(int kc=0;kc<4;kc++) af[kc] = *(bf16x8*)&inter[1][wv*16+il][ql*8 + kc*32];
  __syncthreads();
  #pragma unroll
  for(int nj=0;nj<8;nj++) acc[nj] = (f32x4){0.f,0.f,0.f,0.f};
  #pragma unroll
  for(int kc=0;kc<4;kc++)
    #pragma unroll
    for(int nj=0;nj<8;nj++){
      bf16x8 bb = *(bf16x8*)&WsF[((kc*8+nj)*64 + lane)*8];
      acc[nj] = __builtin_amdgcn_mfma_f32_16x16x32_bf16(af[kc], bb, acc[nj], 0,0,0);
    }
  {
    float bl8[8]; loadbias(b3, bl8);
    float lg8[8], lb8[8];
    loadbias(lng, lg8); loadbias(lnb, lb8);
    #pragma unroll
    for(int r=0;r<4;r++){
      int rr = row0 + wv*16 + ql*4 + r;
      if(rr >= N) continue;     // uniform across il -> shfl-safe
      bf16x8 rv = *(const bf16x8*)&hn2[(size_t)rr*128 + il*8];
      float t8[8], s1=0.f, s2=0.f;
      #pragma unroll
      for(int nj=0;nj<8;nj++){
        float x = sp_(acc[nj][r] + bl8[nj]) + b2f(rv[nj]);
        t8[nj]=x; s1+=x; s2+=x*x;
      }
      s1 = wsum16(s1); s2 = wsum16(s2);
      float mu = s1*(1.f/128.f);
      float var = s2*(1.f/128.f) - mu*mu;
      float rsg = rsqrtf(var + 1e-5f);
      *(float4*)&hout[(size_t)rr*128 + il*8]     = make_float4(t8[0],t8[1],t8[2],t8[3]);
      *(float4*)&hout[(size_t)rr*128 + il*8 + 4] = make_float4(t8[4],t8[5],t8[6],t8[7]);
      bf16x8 o;
      #pragma unroll
      for(int nj=0;nj<8;nj++) o[nj] = f2bs((t8[nj]-mu)*rsg*lg8[nj] + lb8[nj]);
      *(bf16x8*)&hnout[(size_t)rr*128 + il*8] = o;
    }
  }
}

// ---------------- pooling + output head (block per graph) ----------------
__global__ void pool_head(const float* __restrict__ h, const int* __restrict__ batch,
                          const float* __restrict__ Wo1, const float* __restrict__ bo1,
                          const float* __restrict__ Wo2, const float* __restrict__ bo2,
                          float* __restrict__ out, int N){
  int gid = blockIdx.x;
  int t = threadIdx.x;  // 128 threads
  int lo = lb_(batch, N, gid), hi = lb_(batch, N, gid+1);
  __shared__ float pl[128];
  __shared__ float red[128];
  float s = 0.f;
  for(int i=lo;i<hi;i++) s += h[(size_t)i*HID + t];
  pl[t] = s;
  __syncthreads();
  float acc = bo1[t];
  for(int c=0;c<128;c++) acc = fmaf(pl[c], Wo1[c*HID+t], acc);
  red[t] = sp_(acc)*Wo2[t];
  __syncthreads();
  for(int off=64;off>0;off>>=1){
    if(t<off) red[t]+=red[t+off];
    __syncthreads();
  }
  if(t==0) out[gid] = red[0] + bo2[0];
}

extern "C" void kernel_launch(void* const* d_in, const int* in_sizes, int n_in,
                              void* d_out, int out_size, void* d_ws, size_t ws_size,
                              hipStream_t stream){
  const float* h_in = (const float*)d_in[0];
  const float* pos  = (const float*)d_in[1];
  const float* ew   = (const float*)d_in[2];
  const float* Wq = (const float*)d_in[3];  const float* bq = (const float*)d_in[4];
  const float* Wk = (const float*)d_in[5];  const float* bk = (const float*)d_in[6];
  const float* Wv = (const float*)d_in[7];  const float* bv = (const float*)d_in[8];
  const float* We = (const float*)d_in[9];
  const float* Wsk= (const float*)d_in[10]; const float* bsk=(const float*)d_in[11];
  const float* Wbeta=(const float*)d_in[12];
  const float* W1=(const float*)d_in[13]; const float* b1=(const float*)d_in[14];
  const float* W2=(const float*)d_in[15]; const float* b2=(const float*)d_in[16];
  const float* W3=(const float*)d_in[17]; const float* b3=(const float*)d_in[18];
  const float* lng=(const float*)d_in[19]; const float* lnb=(const float*)d_in[20];
  const float* Wo1=(const float*)d_in[21]; const float* bo1=(const float*)d_in[22];
  const float* Wo2=(const float*)d_in[23]; const float* bo2=(const float*)d_in[24];
  const int* ei    = (const int*)d_in[25];
  const int* batch = (const int*)d_in[26];
  int N = in_sizes[0]/HID;
  int E = in_sizes[2];
  int G = out_size;
  float* out = (float*)d_out;

  char* ws = (char*)d_ws;
  size_t off=0;
  auto alloc=[&](size_t bytes)->char*{
    char* p = ws + off;
    off = (off + bytes + 255) & ~(size_t)255;
    return p;
  };
  float* efs   =(float*)alloc((size_t)E*12*4);
  int* esrc    =(int*)  alloc((size_t)E*4);
  int* csr     =(int*)  alloc((size_t)E*4);
  int* counts  =(int*)  alloc((size_t)N*4);
  int* counts2 =(int*)  alloc((size_t)N*4);
  int* rowst   =(int*)  alloc((size_t)(N+1)*4);
  int* tmp     =(int*)  alloc((size_t)N*4);
  int* bsums   =(int*)  alloc(256*4);
  int* boffs   =(int*)  alloc(256*4);
  __hip_bfloat16* hn   =(__hip_bfloat16*)alloc((size_t)N*HID*2);
  __hip_bfloat16* hn2  =(__hip_bfloat16*)alloc((size_t)N*HID*2);
  __hip_bfloat16* qsb  =(__hip_bfloat16*)alloc((size_t)N*256*2);
  __hip_bfloat16* kvb  =(__hip_bfloat16*)alloc((size_t)N*256*2);
  float* qwb   =(float*)alloc((size_t)N*48*4);
  float* att   =(float*)alloc((size_t)N*HID*4);
  float* hcur  =(float*)alloc((size_t)N*HID*4);
  __hip_bfloat16* Wqkvs_t =(__hip_bfloat16*)alloc((size_t)NLAYER*5*16384*2);
  __hip_bfloat16* Wffn_t  =(__hip_bfloat16*)alloc((size_t)NLAYER*3*16384*2);
  float* bqkvs =(float*)alloc((size_t)NLAYER*640*4);
  size_t ws_used = off;

  int ebl = (E+255)/256;
  int nb  = (N+255)/256;
  int nwb = (N+3)/4;
  int nrb128 = (N+127)/128;
  int nrb64  = (N+63)/64;
  dim3 gqkvs(5, nrb128);

  // Normalize ALL workspace state inside the captured graph: validation call,
  // graph replays, and tripwire then compute from an identical ws image,
  // eliminating the first-call vs post-timing output divergence.
  hipMemsetAsync(ws, 0, (ws_used <= ws_size ? ws_used : ws_size), stream);

  count_dst<<<ebl,256,0,stream>>>(ei,counts,E);
  scan1<<<nb,256,0,stream>>>(counts,tmp,bsums,N);
  scan2<<<1,256,0,stream>>>(bsums,boffs,nb);
  finalize_rs<<<nb,256,0,stream>>>(tmp,boffs,rowst,N);
  csr_scatter<<<ebl,256,0,stream>>>(ei,rowst,counts2,csr,E);
  sort_seg<<<nb,256,0,stream>>>(rowst,csr,N);          // deterministic order
  edge_feat<<<ebl,256,0,stream>>>(pos,ew,ei,csr,efs,esrc,E);
  {
    int tot = NLAYER*5*16384 + NLAYER*3*16384 + NLAYER*640;
    pack_w<<<(tot+255)/256,256,0,stream>>>(Wq,Wk,Wv,Wsk,bq,bk,bv,bsk,We,W1,W2,W3,
                                           Wqkvs_t,bqkvs,Wffn_t);
  }

  ln_node<<<nwb,256,0,stream>>>(h_in,lng,lnb,hn,N);
  for(int l=0;l<NLAYER;l++){
    const float* We_l = We + (size_t)l*(KRBF+1)*HID;
    const float* Wb_l = Wbeta + (size_t)l*3*HID;
    const float* b1_l = b1 + (size_t)l*HID;
    const float* b2_l = b2 + (size_t)l*HID;
    const float* b3_l = b3 + (size_t)l*HID;

    gemm_qkvs<<<gqkvs,256,0,stream>>>(hn, Wqkvs_t + (size_t)l*5*16384,
                                      bqkvs + l*640, qsb, kvb, qwb, N);
    attn_fused6<<<nwb,256,0,stream>>>(qsb,kvb,qwb,efs,esrc,We_l,rowst,att,N);
    combine_ln<<<nwb,256,0,stream>>>(att,qsb,hn,Wb_l,lng,lnb,hn2,N);
    ffn_fused<<<nrb64,256,0,stream>>>(hn2, Wffn_t + (size_t)l*3*16384,
                                      b1_l,b2_l,b3_l,lng,lnb,hcur,hn,N);
  }
  pool_head<<<G,128,0,stream>>>(hcur,batch,Wo1,bo1,Wo2,bo2,out,N);
}